// Round 7
// baseline (411.120 us; speedup 1.0000x reference)
//
#include <hip/hip_runtime.h>

// Problem constants
#define BATCH 2
#define SEQ   2048
#define DMODEL 1024
#define NHEAD 16
#define DK    64
#define MROWS (BATCH * SEQ)   // 4096
#define KSPLIT 4

using bf16x8 = __attribute__((ext_vector_type(8))) short;  // 8 bf16 (4 VGPRs)
using f32x4  = __attribute__((ext_vector_type(4))) float;  // MFMA C/D

__device__ __forceinline__ unsigned short f2bf_rne(float x) {
    unsigned u = __float_as_uint(x);
    u += 0x7FFFu + ((u >> 16) & 1u);
    return (unsigned short)(u >> 16);
}
__device__ __forceinline__ float bf2f(unsigned short h) {
    return __uint_as_float((unsigned)h << 16);
}

// Fragment-major layout for the MFMA A operand (Q), indexed by GLOBAL row.
__device__ __forceinline__ long long qf_addr(int row, int d) {
    const int qt = row >> 4, lid = row & 15;
    const int hh = d >> 6, ch = (d >> 3) & 7, j = d & 7;
    return ((((long long)qt * NHEAD + hh) * 8 + ch) * 16 + lid) * 8 + j;
}

// ---------------------------------------------------------------------------
// Elementwise split fp32 -> (hi, lo) bf16.  n must be /1024.
// ---------------------------------------------------------------------------
__global__ __launch_bounds__(256) void conv_split_kernel(
    const float* __restrict__ x, unsigned short* __restrict__ hi,
    unsigned short* __restrict__ lo)
{
    const long long i = ((long long)blockIdx.x * 256 + threadIdx.x) * 4;
    float4 v = *(const float4*)&x[i];
    ushort4 h4, l4;
    unsigned short h;
    h = f2bf_rne(v.x); h4.x = h; l4.x = f2bf_rne(v.x - bf2f(h));
    h = f2bf_rne(v.y); h4.y = h; l4.y = f2bf_rne(v.y - bf2f(h));
    h = f2bf_rne(v.z); h4.z = h; l4.z = f2bf_rne(v.z - bf2f(h));
    h = f2bf_rne(v.w); h4.w = h; l4.w = f2bf_rne(v.w - bf2f(h));
    *(ushort4*)&hi[i] = h4;
    *(ushort4*)&lo[i] = l4;
}

// ---------------------------------------------------------------------------
// Transpose + split: W[K=1024][N=1024] fp32 -> WT hi/lo [N][K] bf16.
// 64x64 tile per block via LDS.
// ---------------------------------------------------------------------------
__global__ __launch_bounds__(256) void conv_splitT_kernel(
    const float* __restrict__ W, unsigned short* __restrict__ hiT,
    unsigned short* __restrict__ loT)
{
    const int k0 = blockIdx.y * 64;
    const int n0 = blockIdx.x * 64;
    const int tid = threadIdx.x;
    __shared__ float T[64][68];
#pragma unroll
    for (int it = 0; it < 4; ++it) {
        const int r = it * 16 + (tid >> 4);
        const int c = (tid & 15) * 4;
        float4 v = *(const float4*)&W[(long long)(k0 + r) * DMODEL + n0 + c];
        T[r][c] = v.x; T[r][c + 1] = v.y; T[r][c + 2] = v.z; T[r][c + 3] = v.w;
    }
    __syncthreads();
#pragma unroll
    for (int it = 0; it < 4; ++it) {
        const int n = it * 16 + (tid >> 4);
        const int kc = (tid & 15) * 4;
        ushort4 h4, l4;
        float v; unsigned short h;
        v = T[kc + 0][n]; h = f2bf_rne(v); h4.x = h; l4.x = f2bf_rne(v - bf2f(h));
        v = T[kc + 1][n]; h = f2bf_rne(v); h4.y = h; l4.y = f2bf_rne(v - bf2f(h));
        v = T[kc + 2][n]; h = f2bf_rne(v); h4.z = h; l4.z = f2bf_rne(v - bf2f(h));
        v = T[kc + 3][n]; h = f2bf_rne(v); h4.w = h; l4.w = f2bf_rne(v - bf2f(h));
        const long long off = (long long)(n0 + n) * DMODEL + k0 + kc;
        *(ushort4*)&hiT[off] = h4;
        *(ushort4*)&loT[off] = l4;
    }
}

// ---------------------------------------------------------------------------
// Split-bf16 MFMA projection GEMM: C = A @ W + bias,  M=4096, N=K=1024.
// A as (AH,AL) row-major [M][K]; W as transposed (BTH,BTL) [N][K].
// 128x128 C-tile, 4 waves (2x2 of 64x64), K-chunk 32, 3-term split product.
// Epilogue: fragQ ? fragment-major Q hi/lo : row-major K hi/lo.
// ---------------------------------------------------------------------------
#define PROW 40   // ushorts per LDS row (32 payload + 8 pad -> 80 B pitch)

__global__ __launch_bounds__(256) void proj_mfma_kernel(
    const unsigned short* __restrict__ AH, const unsigned short* __restrict__ AL,
    const unsigned short* __restrict__ BTH, const unsigned short* __restrict__ BTL,
    const float* __restrict__ bias,
    unsigned short* __restrict__ OH, unsigned short* __restrict__ OL, int fragQ)
{
    const int n0 = blockIdx.x * 128;
    const int m0 = blockIdx.y * 128;
    const int tid = threadIdx.x;
    const int w = tid >> 6, lane = tid & 63;
    const int wm = w >> 1, wn = w & 1;
    const int quad = lane >> 4, lid = lane & 15;

    __shared__ unsigned short As[2][128][PROW];   // 20 KB
    __shared__ unsigned short Bs[2][128][PROW];   // 20 KB

    f32x4 acc[4][4] = {};

    for (int k0 = 0; k0 < DMODEL; k0 += 32) {
        __syncthreads();
#pragma unroll
        for (int it = 0; it < 4; ++it) {
            const int cell = it * 256 + tid;          // 1024 cells of 16 B
            const int half = cell >> 9;
            const int row  = (cell >> 2) & 127;
            const int c    = cell & 3;
            const unsigned short* a = half ? AL : AH;
            uint4 v = *(const uint4*)&a[(long long)(m0 + row) * DMODEL + k0 + c * 8];
            *(uint4*)&As[half][row][c * 8] = v;
            const unsigned short* b = half ? BTL : BTH;
            uint4 u = *(const uint4*)&b[(long long)(n0 + row) * DMODEL + k0 + c * 8];
            *(uint4*)&Bs[half][row][c * 8] = u;
        }
        __syncthreads();

        bf16x8 af[2][4], bf_[2][4];
#pragma unroll
        for (int mt = 0; mt < 4; ++mt) {
            const int r = wm * 64 + mt * 16 + lid;
            af[0][mt] = *(const bf16x8*)&As[0][r][quad * 8];
            af[1][mt] = *(const bf16x8*)&As[1][r][quad * 8];
        }
#pragma unroll
        for (int nt = 0; nt < 4; ++nt) {
            const int r = wn * 64 + nt * 16 + lid;
            bf_[0][nt] = *(const bf16x8*)&Bs[0][r][quad * 8];
            bf_[1][nt] = *(const bf16x8*)&Bs[1][r][quad * 8];
        }
#pragma unroll
        for (int mt = 0; mt < 4; ++mt)
#pragma unroll
            for (int nt = 0; nt < 4; ++nt) {
                acc[mt][nt] = __builtin_amdgcn_mfma_f32_16x16x32_bf16(af[0][mt], bf_[0][nt], acc[mt][nt], 0, 0, 0);
                acc[mt][nt] = __builtin_amdgcn_mfma_f32_16x16x32_bf16(af[0][mt], bf_[1][nt], acc[mt][nt], 0, 0, 0);
                acc[mt][nt] = __builtin_amdgcn_mfma_f32_16x16x32_bf16(af[1][mt], bf_[0][nt], acc[mt][nt], 0, 0, 0);
            }
    }

    float bv[4];
#pragma unroll
    for (int nt = 0; nt < 4; ++nt)
        bv[nt] = bias[n0 + wn * 64 + nt * 16 + lid];

#pragma unroll
    for (int mt = 0; mt < 4; ++mt)
#pragma unroll
        for (int nt = 0; nt < 4; ++nt) {
            const int col = n0 + wn * 64 + nt * 16 + lid;
#pragma unroll
            for (int r = 0; r < 4; ++r) {
                const int row = m0 + wm * 64 + mt * 16 + quad * 4 + r;
                const float val = acc[mt][nt][r] + bv[nt];
                const unsigned short h = f2bf_rne(val);
                const unsigned short l = f2bf_rne(val - bf2f(h));
                if (fragQ) {
                    const long long fa = qf_addr(row, col);
                    OH[fa] = h; OL[fa] = l;
                } else {
                    const long long off = (long long)row * DMODEL + col;
                    OH[off] = h; OL[off] = l;
                }
            }
        }
}

// ---------------------------------------------------------------------------
// fp32 tiled GEMM (still used for out proj).
// ---------------------------------------------------------------------------
__global__ __launch_bounds__(256) void gemm_bias_kernel(
    const float* __restrict__ A, long long sA,
    const float* __restrict__ W, long long sW,
    const float* __restrict__ bias,
    float* __restrict__ C, long long sC,
    int M, int N, int K)
{
    A += (long long)blockIdx.z * sA;
    W += (long long)blockIdx.z * sW;
    C += (long long)blockIdx.z * sC;
    const int n0 = blockIdx.x * 64;
    const int m0 = blockIdx.y * 64;

    __shared__ float As[16][68];
    __shared__ float Bs[16][68];

    const int tid = threadIdx.x;
    const int tm = (tid >> 4) << 2;
    const int tn = (tid & 15) << 2;
    const int arow = tid >> 2, ak = (tid & 3) << 2;
    const int brow = tid >> 4, bn = (tid & 15) << 2;

    float acc[4][4] = {};

    for (int k0 = 0; k0 < K; k0 += 16) {
        float4 av = *(const float4*)&A[(long long)(m0 + arow) * K + k0 + ak];
        float4 wv = *(const float4*)&W[(long long)(k0 + brow) * N + n0 + bn];
        As[ak + 0][arow] = av.x;
        As[ak + 1][arow] = av.y;
        As[ak + 2][arow] = av.z;
        As[ak + 3][arow] = av.w;
        *(float4*)&Bs[brow][bn] = wv;
        __syncthreads();
#pragma unroll
        for (int kk = 0; kk < 16; ++kk) {
            float4 a4 = *(const float4*)&As[kk][tm];
            float4 b4 = *(const float4*)&Bs[kk][tn];
            float aa[4] = {a4.x, a4.y, a4.z, a4.w};
            float bb[4] = {b4.x, b4.y, b4.z, b4.w};
#pragma unroll
            for (int i = 0; i < 4; ++i)
#pragma unroll
                for (int j = 0; j < 4; ++j)
                    acc[i][j] = fmaf(aa[i], bb[j], acc[i][j]);
        }
        __syncthreads();
    }

    float4 bv = make_float4(0.f, 0.f, 0.f, 0.f);
    if (bias) bv = *(const float4*)&bias[n0 + tn];
#pragma unroll
    for (int i = 0; i < 4; ++i) {
        float4 o = make_float4(acc[i][0] + bv.x, acc[i][1] + bv.y,
                               acc[i][2] + bv.z, acc[i][3] + bv.w);
        *(float4*)&C[(long long)(m0 + tm + i) * N + n0 + tn] = o;
    }
}

// ---------------------------------------------------------------------------
// Split-K fp32 GEMM: partials P[s][b*M+m][n] = A_b[m, kb:kb+kl] @ W_b[kb:kb+kl, n]
// For skinny-N GEMMs (V proj, avg@V) where the M*N tile count alone cannot
// fill the chip: blockIdx.z = b*nsplit + s gives nsplit x more blocks.
// ---------------------------------------------------------------------------
__global__ __launch_bounds__(256) void gemm_splitk_kernel(
    const float* __restrict__ A, long long sA,
    const float* __restrict__ W, long long sW,
    float* __restrict__ P,
    int M, int N, int K, int nsplit)
{
    const int nbatch = gridDim.z / nsplit;
    const int b = blockIdx.z / nsplit;
    const int s = blockIdx.z % nsplit;
    A += (long long)b * sA;
    W += (long long)b * sW;
    float* Pout = P + ((long long)s * nbatch + b) * M * N;

    const int n0 = blockIdx.x * 64;
    const int m0 = blockIdx.y * 64;
    const int kb = s * (K / nsplit);
    const int kl = K / nsplit;

    __shared__ float As[16][68];
    __shared__ float Bs[16][68];

    const int tid = threadIdx.x;
    const int tm = (tid >> 4) << 2;
    const int tn = (tid & 15) << 2;
    const int arow = tid >> 2, ak = (tid & 3) << 2;
    const int brow = tid >> 4, bn = (tid & 15) << 2;

    float acc[4][4] = {};

    for (int k0 = 0; k0 < kl; k0 += 16) {
        float4 av = *(const float4*)&A[(long long)(m0 + arow) * K + kb + k0 + ak];
        float4 wv = *(const float4*)&W[(long long)(kb + k0 + brow) * N + n0 + bn];
        As[ak + 0][arow] = av.x;
        As[ak + 1][arow] = av.y;
        As[ak + 2][arow] = av.z;
        As[ak + 3][arow] = av.w;
        *(float4*)&Bs[brow][bn] = wv;
        __syncthreads();
#pragma unroll
        for (int kk = 0; kk < 16; ++kk) {
            float4 a4 = *(const float4*)&As[kk][tm];
            float4 b4 = *(const float4*)&Bs[kk][tn];
            float aa[4] = {a4.x, a4.y, a4.z, a4.w};
            float bb[4] = {b4.x, b4.y, b4.z, b4.w};
#pragma unroll
            for (int i = 0; i < 4; ++i)
#pragma unroll
                for (int j = 0; j < 4; ++j)
                    acc[i][j] = fmaf(aa[i], bb[j], acc[i][j]);
        }
        __syncthreads();
    }

#pragma unroll
    for (int i = 0; i < 4; ++i) {
        float4 o = make_float4(acc[i][0], acc[i][1], acc[i][2], acc[i][3]);
        *(float4*)&Pout[(long long)(m0 + tm + i) * N + n0 + tn] = o;
    }
}

// C[i] = bias[i % N] + sum_s P[s*stride + i]   (vectorized, bias optional)
__global__ __launch_bounds__(256) void reduce_bias_kernel(
    const float* __restrict__ P, const float* __restrict__ bias,
    float* __restrict__ C, long long stride, int nsplit, int N)
{
    const long long i = ((long long)blockIdx.x * 256 + threadIdx.x) * 4;
    float4 s = *(const float4*)&P[i];
    for (int k = 1; k < nsplit; ++k) {
        float4 v = *(const float4*)&P[(long long)k * stride + i];
        s.x += v.x; s.y += v.y; s.z += v.z; s.w += v.w;
    }
    if (bias) {
        const int n = (int)(i % N);
        float4 b4 = *(const float4*)&bias[n];
        s.x += b4.x; s.y += b4.y; s.z += b4.z; s.w += b4.w;
    }
    *(float4*)&C[i] = s;
}

// ---------------------------------------------------------------------------
// Direct global->LDS staging of one 128-key x 64-d (hi+lo) K tile, 32 KB,
// by an 8-wave (512-thread) block.  Zero VGPRs hold staged data.
//
// LDS layout (linear, unpadded -- required by global_load_lds): tile =
// hi[8192 ushorts] ++ lo[8192]; within a half, phys ushort idx =
// row*64 + physslot*8, with 16B-slot XOR swizzle physslot = slot ^ (row&7)
// (T2 / rule 21: same involution pre-applied to the per-lane GLOBAL source
// and to the read address; hardware LDS write stays linear).
// ---------------------------------------------------------------------------
#define HALF_USH 8192
#define TILE_USH 16384   // 32 KB

__device__ __forceinline__ void stage_issue(
    const unsigned short* __restrict__ Khi, const unsigned short* __restrict__ Klo,
    unsigned short* KsBuf, long long grow0, int h, int w, int lane)
{
    const int rsub = lane >> 3;            // row within 8-row chunk
    const int slot = (lane & 7) ^ rsub;    // logical 16B slot this lane fetches
#pragma unroll
    for (int it = 0; it < 4; ++it) {
        const int c = it * 8 + w;          // chunk 0..31 (wave-uniform), 1 KB each
        const int half = c >> 4;
        const int row  = (c & 15) * 8 + rsub;
        const unsigned short* src = half ? Klo : Khi;
        const unsigned short* g = &src[(grow0 + row) * DMODEL + h * 64 + slot * 8];
        __builtin_amdgcn_global_load_lds(
            (const __attribute__((address_space(1))) unsigned int*)g,
            (__attribute__((address_space(3))) unsigned int*)(KsBuf + c * 512),
            16, 0, 0);
    }
}

__device__ __forceinline__ f32x4 mfma3(bf16x8 ah, bf16x8 al, bf16x8 bh, bf16x8 bl, f32x4 s) {
    s = __builtin_amdgcn_mfma_f32_16x16x32_bf16(ah, bh, s, 0, 0, 0);
    s = __builtin_amdgcn_mfma_f32_16x16x32_bf16(ah, bl, s, 0, 0, 0);
    s = __builtin_amdgcn_mfma_f32_16x16x32_bf16(al, bh, s, 0, 0, 0);
    return s;
}

// ---------------------------------------------------------------------------
// Stats: partial row-sums of exp(QK^T/8) into lsum (atomicAdd, k-split=4).
// 512 threads: 8 waves x 32 q-rows (mt=2) -> Q-tile 256, 128-key K tiles.
// (R5 configuration -- best measured for this kernel.)
// ---------------------------------------------------------------------------
__global__ __launch_bounds__(512, 4) void attn_stats_kernel(
    const unsigned short* __restrict__ QfH, const unsigned short* __restrict__ QfL,
    const unsigned short* __restrict__ Khi, const unsigned short* __restrict__ Klo,
    float* __restrict__ lsum)
{
    const int q0 = blockIdx.x * 256;
    const int h  = blockIdx.y;
    const int b  = blockIdx.z >> 2;
    const int kbase = (blockIdx.z & 3) * (SEQ / KSPLIT);
    const int tid = threadIdx.x;
    const int w = tid >> 6, lane = tid & 63;
    const int quad = lane >> 4, lid = lane & 15;

    __shared__ unsigned short Ks[2 * TILE_USH];   // 64 KB, double buffer

    bf16x8 ah[2][2], al[2][2];
#pragma unroll
    for (int mt = 0; mt < 2; ++mt) {
        const long long qt = (long long)(b * SEQ + q0) / 16 + w * 2 + mt;
#pragma unroll
        for (int ks = 0; ks < 2; ++ks) {
            const long long fa = (((qt * NHEAD + h) * 8 + (quad + 4 * ks)) * 16 + lid) * 8;
            ah[mt][ks] = *(const bf16x8*)&QfH[fa];
            al[mt][ks] = *(const bf16x8*)&QfL[fa];
        }
    }

    float ls[2][4] = {};
    const long long grow0 = (long long)b * SEQ + kbase;

    stage_issue(Khi, Klo, Ks, grow0, h, w, lane);
    __syncthreads();                       // buf0 ready (vmcnt drain)

    for (int kc = 0; kc < SEQ / KSPLIT; kc += 128) {
        const int buf = (kc >> 7) & 1;
        if (kc + 128 < SEQ / KSPLIT)
            stage_issue(Khi, Klo, Ks + (buf ^ 1) * TILE_USH,
                        grow0 + kc + 128, h, w, lane);   // flies under compute
        const unsigned short* Kc = Ks + buf * TILE_USH;

#pragma unroll
        for (int kt = 0; kt < 8; ++kt) {
            const int rr = kt * 16 + lid;
            const int sw = rr & 7;
            bf16x8 bh[2], bl[2];
#pragma unroll
            for (int ks = 0; ks < 2; ++ks) {
                const int o = rr * 64 + (((quad + 4 * ks) ^ sw) * 8);
                bh[ks] = *(const bf16x8*)&Kc[o];
                bl[ks] = *(const bf16x8*)&Kc[HALF_USH + o];
            }
#pragma unroll
            for (int mt = 0; mt < 2; ++mt) {
                f32x4 s = {0.f, 0.f, 0.f, 0.f};
#pragma unroll
                for (int ks = 0; ks < 2; ++ks)
                    s = mfma3(ah[mt][ks], al[mt][ks], bh[ks], bl[ks], s);
#pragma unroll
                for (int r = 0; r < 4; ++r)
                    ls[mt][r] += __expf(s[r] * 0.125f);
            }
        }
        __syncthreads();                   // next buf loaded; cur free to overwrite
    }

#pragma unroll
    for (int off = 1; off < 16; off <<= 1)
#pragma unroll
        for (int mt = 0; mt < 2; ++mt)
#pragma unroll
            for (int r = 0; r < 4; ++r)
                ls[mt][r] += __shfl_xor(ls[mt][r], off);

    if (lid == 0) {
        const long long base = ((long long)(b * NHEAD + h)) * SEQ + q0 + w * 32 + quad * 4;
#pragma unroll
        for (int mt = 0; mt < 2; ++mt)
#pragma unroll
            for (int r = 0; r < 4; ++r)
                atomicAdd(&lsum[base + mt * 16 + r], ls[mt][r]);
    }
}

// lsum -> c = 1/(16*l)
__global__ __launch_bounds__(256) void recip_kernel(float* __restrict__ p) {
    const int i = blockIdx.x * 256 + threadIdx.x;
    p[i] = 0.0625f / p[i];
}

// ---------------------------------------------------------------------------
// Avg: block owns 128x128 (q,k) tile; loops 16 heads.  512 threads: 8 waves
// arranged as 4 q-waves x 2 k-halves -- wave (wq,wk) covers 32 q-rows
// (mt=2) x 64 k-cols (kt=4) of the staged 128-key tile.  This keeps all
// three levers at once: mt=2 halves per-q-row LDS reads, the 128-key stage
// keeps compute-per-barrier high, and grid = 16x16x2 = 512 blocks = 2/CU
// (64 KB dbuf, VGPR<=128 at (512,4)) restores cross-block TLP.
// Per-CU head-interval: MFMA 3725 cyc > LDS 2048 > VALU ~2000 -> MFMA-bound.
// ---------------------------------------------------------------------------
__global__ __launch_bounds__(512, 4) void attn_avg_kernel(
    const unsigned short* __restrict__ QfH, const unsigned short* __restrict__ QfL,
    const unsigned short* __restrict__ Khi, const unsigned short* __restrict__ Klo,
    const float* __restrict__ cIn, float* __restrict__ avg)
{
    const int q0 = blockIdx.x * 128;
    const int k0 = blockIdx.y * 128;
    const int b  = blockIdx.z;
    const int tid = threadIdx.x;
    const int w = tid >> 6, lane = tid & 63;
    const int wq = w >> 1, wk = w & 1;
    const int quad = lane >> 4, lid = lane & 15;

    __shared__ unsigned short Ks[2 * TILE_USH];   // 64 KB, double buffer

    f32x4 acc[2][4] = {};                  // [mt][kt] over 32q x 64k
    const long long grow0 = (long long)b * SEQ + k0;

    stage_issue(Khi, Klo, Ks, grow0, 0, w, lane);
    __syncthreads();                       // buf0 ready

    for (int h = 0; h < NHEAD; ++h) {
        // Q frags + per-row softmax scale for head h (issued before the LDS
        // loads so the tile loads stay in flight behind them).
        bf16x8 ah[2][2], al[2][2];
        float c_[2][4];
#pragma unroll
        for (int mt = 0; mt < 2; ++mt) {
            const long long qt = (long long)(b * SEQ + q0) / 16 + wq * 2 + mt;
#pragma unroll
            for (int ks = 0; ks < 2; ++ks) {
                const long long fa = (((qt * NHEAD + h) * 8 + (quad + 4 * ks)) * 16 + lid) * 8;
                ah[mt][ks] = *(const bf16x8*)&QfH[fa];
                al[mt][ks] = *(const bf16x8*)&QfL[fa];
            }
            const long long cb = ((long long)(b * NHEAD + h)) * SEQ + q0 + wq * 32 + mt * 16 + quad * 4;
#pragma unroll
            for (int r = 0; r < 4; ++r)
                c_[mt][r] = cIn[cb + r];
        }

        const int buf = h & 1;
        if (h + 1 < NHEAD)
            stage_issue(Khi, Klo, Ks + (buf ^ 1) * TILE_USH,
                        grow0, h + 1, w, lane);          // flies under compute
        const unsigned short* Kc = Ks + buf * TILE_USH;

#pragma unroll
        for (int kt = 0; kt < 4; ++kt) {
            const int rr = wk * 64 + kt * 16 + lid;      // this wave's k-half
            const int sw = rr & 7;
            bf16x8 bh[2], bl[2];
#pragma unroll
            for (int ks = 0; ks < 2; ++ks) {
                const int o = rr * 64 + (((quad + 4 * ks) ^ sw) * 8);
                bh[ks] = *(const bf16x8*)&Kc[o];
                bl[ks] = *(const bf16x8*)&Kc[HALF_USH + o];
            }
#pragma unroll
            for (int mt = 0; mt < 2; ++mt) {
                f32x4 s = {0.f, 0.f, 0.f, 0.f};
#pragma unroll
                for (int ks = 0; ks < 2; ++ks)
                    s = mfma3(ah[mt][ks], al[mt][ks], bh[ks], bl[ks], s);
#pragma unroll
                for (int r = 0; r < 4; ++r)
                    acc[mt][kt][r] = fmaf(__expf(s[r] * 0.125f), c_[mt][r], acc[mt][kt][r]);
            }
        }
        __syncthreads();                   // next buf loaded; cur free
    }

#pragma unroll
    for (int mt = 0; mt < 2; ++mt)
#pragma unroll
        for (int kt = 0; kt < 4; ++kt)
#pragma unroll
            for (int r = 0; r < 4; ++r) {
                const int q = q0 + wq * 32 + mt * 16 + quad * 4 + r;
                avg[((long long)(b * SEQ + q)) * SEQ + k0 + wk * 64 + kt * 16 + lid] = acc[mt][kt][r];
            }
}

// ---------------------------------------------------------------------------
extern "C" void kernel_launch(void* const* d_in, const int* in_sizes, int n_in,
                              void* d_out, int out_size, void* d_ws, size_t ws_size,
                              hipStream_t stream)
{
    const float* query = (const float*)d_in[0];
    const float* key   = (const float*)d_in[1];
    const float* value = (const float*)d_in[2];
    const float* Wq    = (const float*)d_in[3];
    const float* bq    = (const float*)d_in[4];
    const float* Wk    = (const float*)d_in[5];
    const float* bk    = (const float*)d_in[6];
    const float* Wv    = (const float*)d_in[7];
    const float* bv    = (const float*)d_in[8];
    const float* Wo    = (const float*)d_in[9];
    const float* bo    = (const float*)d_in[10];

    float* out = (float*)d_out;                         // [B,S,DMODEL]
    float* avg = out + (long long)BATCH * SEQ * DMODEL; // [B,S,S]

    const long long QKN = (long long)MROWS * DMODEL;    // 4.2M elems
    unsigned short* QfH = (unsigned short*)d_ws;        // frag-major, 8 MB each
    unsigned short* QfL = QfH + QKN;
    unsigned short* Khi = QfL + QKN;                    // row-major
    unsigned short* Klo = Khi + QKN;
    unsigned short* AspH = Klo + QKN;                   // split input scratch (reused)
    unsigned short* AspL = AspH + QKN;
    unsigned short* WTh  = AspL + QKN;                  // W^T split, 2 MB each
    unsigned short* WTl  = WTh + (long long)DMODEL * DMODEL;
    float* Vb   = (float*)(WTl + (long long)DMODEL * DMODEL); // 4096x64 fp32
    float* lBuf = Vb + (long long)MROWS * DK;                 // B*H*S
    float* ao   = lBuf + (long long)BATCH * NHEAD * SEQ;      // 4096x64

    // Dead-region reuse for split-K partials (in-stream ordering guarantees):
    //  - V proj partials (16 x 1 MB) live in AspH..AspL (dead after proj_mfma(K)).
    //  - avg@V partials (32 x 1 MB) live in QfH..Klo (dead after attn_avg).
    float* Pv  = (float*)AspH;
    float* Pav = (float*)QfH;

    dim3 blk(256);
    hipMemsetAsync(lBuf, 0, (size_t)BATCH * NHEAD * SEQ * sizeof(float), stream);

    const int convGrid = (int)(QKN / (256 * 4));        // 4096
    dim3 tGrid(DMODEL / 64, DMODEL / 64);               // 16x16
    dim3 pGrid(DMODEL / 128, MROWS / 128);              // 8x32

    // Q projection (MFMA split-bf16), emits fragment-major Q hi/lo.
    conv_split_kernel<<<convGrid, blk, 0, stream>>>(query, AspH, AspL);
    conv_splitT_kernel<<<tGrid, blk, 0, stream>>>(Wq, WTh, WTl);
    proj_mfma_kernel<<<pGrid, blk, 0, stream>>>(AspH, AspL, WTh, WTl, bq, QfH, QfL, 1);

    // K projection (MFMA split-bf16), emits row-major K hi/lo.  Scratch reused.
    conv_split_kernel<<<convGrid, blk, 0, stream>>>(key, AspH, AspL);
    conv_splitT_kernel<<<tGrid, blk, 0, stream>>>(Wk, WTh, WTl);
    proj_mfma_kernel<<<pGrid, blk, 0, stream>>>(AspH, AspL, WTh, WTl, bk, Khi, Klo, 0);

    // V projection: split-K fp32 (16 splits -> 1024 blocks), then reduce+bias.
    gemm_splitk_kernel<<<dim3(DK / 64, MROWS / 64, 16), blk, 0, stream>>>(
        value, 0, Wv, 0, Pv, MROWS, DK, DMODEL, 16);
    reduce_bias_kernel<<<dim3((int)((long long)MROWS * DK / 1024)), blk, 0, stream>>>(
        Pv, bv, Vb, (long long)MROWS * DK, 16, DK);

    // Softmax denominators (k-split partial sums), then reciprocal.
    attn_stats_kernel<<<dim3(SEQ / 256, NHEAD, BATCH * KSPLIT), dim3(512), 0, stream>>>(
        QfH, QfL, Khi, Klo, lBuf);
    recip_kernel<<<dim3(BATCH * NHEAD * SEQ / 256), blk, 0, stream>>>(lBuf);

    // Head-averaged attention matrix.
    attn_avg_kernel<<<dim3(SEQ / 128, SEQ / 128, BATCH), dim3(512), 0, stream>>>(
        QfH, QfL, Khi, Klo, lBuf, avg);

    // attn_output = avg_attn @ V: split-K fp32 (32 splits x 2 batches -> 2048
    // blocks) into dead Qf/K region, then reduce (no bias).
    gemm_splitk_kernel<<<dim3(DK / 64, SEQ / 64, BATCH * 32), blk, 0, stream>>>(
        avg, (long long)SEQ * SEQ, Vb, (long long)SEQ * DK, Pav, SEQ, DK, SEQ, 32);
    reduce_bias_kernel<<<dim3((int)((long long)MROWS * DK / 1024)), blk, 0, stream>>>(
        Pav, nullptr, ao, (long long)MROWS * DK, 32, DK);

    // output = attn_output @ Wo + bo
    gemm_bias_kernel<<<dim3(DMODEL / 64, MROWS / 64, 1), blk, 0, stream>>>(
        ao, 0, Wo, 0, bo, out, 0, MROWS, DMODEL, DK);
}

// Round 8
// 359.089 us; speedup vs baseline: 1.1449x; 1.1449x over previous
//
#include <hip/hip_runtime.h>

// Problem constants
#define BATCH 2
#define SEQ   2048
#define DMODEL 1024
#define NHEAD 16
#define DK    64
#define MROWS (BATCH * SEQ)   // 4096
#define KSPLIT 4

using bf16x8 = __attribute__((ext_vector_type(8))) short;  // 8 bf16 (4 VGPRs)
using f32x4  = __attribute__((ext_vector_type(4))) float;  // MFMA C/D

__device__ __forceinline__ unsigned short f2bf_rne(float x) {
    unsigned u = __float_as_uint(x);
    u += 0x7FFFu + ((u >> 16) & 1u);
    return (unsigned short)(u >> 16);
}
__device__ __forceinline__ float bf2f(unsigned short h) {
    return __uint_as_float((unsigned)h << 16);
}

// Fragment-major layout for the MFMA A operand (Q), indexed by GLOBAL row.
__device__ __forceinline__ long long qf_addr(int row, int d) {
    const int qt = row >> 4, lid = row & 15;
    const int hh = d >> 6, ch = (d >> 3) & 7, j = d & 7;
    return ((((long long)qt * NHEAD + hh) * 8 + ch) * 16 + lid) * 8 + j;
}

// ---------------------------------------------------------------------------
// Elementwise split fp32 -> (hi, lo) bf16.  n must be /1024.
// ---------------------------------------------------------------------------
__global__ __launch_bounds__(256) void conv_split_kernel(
    const float* __restrict__ x, unsigned short* __restrict__ hi,
    unsigned short* __restrict__ lo)
{
    const long long i = ((long long)blockIdx.x * 256 + threadIdx.x) * 4;
    float4 v = *(const float4*)&x[i];
    ushort4 h4, l4;
    unsigned short h;
    h = f2bf_rne(v.x); h4.x = h; l4.x = f2bf_rne(v.x - bf2f(h));
    h = f2bf_rne(v.y); h4.y = h; l4.y = f2bf_rne(v.y - bf2f(h));
    h = f2bf_rne(v.z); h4.z = h; l4.z = f2bf_rne(v.z - bf2f(h));
    h = f2bf_rne(v.w); h4.w = h; l4.w = f2bf_rne(v.w - bf2f(h));
    *(ushort4*)&hi[i] = h4;
    *(ushort4*)&lo[i] = l4;
}

// ---------------------------------------------------------------------------
// Transpose + split: W[K=1024][N=1024] fp32 -> WT hi/lo [N][K] bf16.
// 64x64 tile per block via LDS.
// ---------------------------------------------------------------------------
__global__ __launch_bounds__(256) void conv_splitT_kernel(
    const float* __restrict__ W, unsigned short* __restrict__ hiT,
    unsigned short* __restrict__ loT)
{
    const int k0 = blockIdx.y * 64;
    const int n0 = blockIdx.x * 64;
    const int tid = threadIdx.x;
    __shared__ float T[64][68];
#pragma unroll
    for (int it = 0; it < 4; ++it) {
        const int r = it * 16 + (tid >> 4);
        const int c = (tid & 15) * 4;
        float4 v = *(const float4*)&W[(long long)(k0 + r) * DMODEL + n0 + c];
        T[r][c] = v.x; T[r][c + 1] = v.y; T[r][c + 2] = v.z; T[r][c + 3] = v.w;
    }
    __syncthreads();
#pragma unroll
    for (int it = 0; it < 4; ++it) {
        const int n = it * 16 + (tid >> 4);
        const int kc = (tid & 15) * 4;
        ushort4 h4, l4;
        float v; unsigned short h;
        v = T[kc + 0][n]; h = f2bf_rne(v); h4.x = h; l4.x = f2bf_rne(v - bf2f(h));
        v = T[kc + 1][n]; h = f2bf_rne(v); h4.y = h; l4.y = f2bf_rne(v - bf2f(h));
        v = T[kc + 2][n]; h = f2bf_rne(v); h4.z = h; l4.z = f2bf_rne(v - bf2f(h));
        v = T[kc + 3][n]; h = f2bf_rne(v); h4.w = h; l4.w = f2bf_rne(v - bf2f(h));
        const long long off = (long long)(n0 + n) * DMODEL + k0 + kc;
        *(ushort4*)&hiT[off] = h4;
        *(ushort4*)&loT[off] = l4;
    }
}

// ---------------------------------------------------------------------------
// Split-bf16 MFMA projection GEMM v2: C = A @ W + bias, M=4096, N=K=1024.
// 64n x 128m tiles -> grid 16x32 = 512 blocks (2/CU).  BK=64.  Staging via
// global_load_lds into linear [rows][64] hi/lo tiles with the 16B-slot XOR
// swizzle (physslot = slot ^ (row&7)) proven 0-conflict in the attention
// kernels.  fp32 accumulation chain order identical to v1 (same 32-k
// sub-chunk sequence, same (hh,hl,lh) term order) -> bit-identical output.
// ---------------------------------------------------------------------------
#define PA_HALF 8192    // ushorts: 128 rows x 64
#define PA_TILE 16384   // 32 KB
#define PB_HALF 4096    // 64 rows x 64
#define PB_TILE 8192    // 16 KB

__global__ __launch_bounds__(256, 2) void proj_mfma_kernel(
    const unsigned short* __restrict__ AH, const unsigned short* __restrict__ AL,
    const unsigned short* __restrict__ BTH, const unsigned short* __restrict__ BTL,
    const float* __restrict__ bias,
    unsigned short* __restrict__ OH, unsigned short* __restrict__ OL, int fragQ)
{
    const int n0 = blockIdx.x * 64;
    const int m0 = blockIdx.y * 128;
    const int tid = threadIdx.x;
    const int w = tid >> 6, lane = tid & 63;
    const int quad = lane >> 4, lid = lane & 15;
    const int rsub = lane >> 3;            // row within 8-row chunk
    const int slot = (lane & 7) ^ rsub;    // logical 16B slot this lane fetches

    __shared__ unsigned short As[PA_TILE];   // 32 KB (hi ++ lo)
    __shared__ unsigned short Bs[PB_TILE];   // 16 KB (hi ++ lo)

    f32x4 acc[2][4] = {};   // wave w owns m rows w*32..w*32+31; all 64 n cols

    for (int kc = 0; kc < DMODEL; kc += 64) {
        __syncthreads();                   // previous compute done, LDS free
        // Stage A-tile: 32 chunks (16 hi + 16 lo) of 8 rows x 128 B.
#pragma unroll
        for (int it = 0; it < 8; ++it) {
            const int c = it * 4 + w;
            const int half = c >> 4;
            const int row  = (c & 15) * 8 + rsub;
            const unsigned short* src = half ? AL : AH;
            const unsigned short* g = &src[(long long)(m0 + row) * DMODEL + kc + slot * 8];
            __builtin_amdgcn_global_load_lds(
                (const __attribute__((address_space(1))) unsigned int*)g,
                (__attribute__((address_space(3))) unsigned int*)(As + c * 512),
                16, 0, 0);
        }
        // Stage B-tile: 16 chunks (8 hi + 8 lo).
#pragma unroll
        for (int it = 0; it < 4; ++it) {
            const int c = it * 4 + w;
            const int half = c >> 3;
            const int row  = (c & 7) * 8 + rsub;
            const unsigned short* src = half ? BTL : BTH;
            const unsigned short* g = &src[(long long)(n0 + row) * DMODEL + kc + slot * 8];
            __builtin_amdgcn_global_load_lds(
                (const __attribute__((address_space(1))) unsigned int*)g,
                (__attribute__((address_space(3))) unsigned int*)(Bs + c * 512),
                16, 0, 0);
        }
        __syncthreads();                   // drains loads; tile ready

#pragma unroll
        for (int ks = 0; ks < 2; ++ks) {   // two 32-k sub-chunks, in k order
            bf16x8 ah[2], al_[2], bh[4], bl[4];
#pragma unroll
            for (int mt = 0; mt < 2; ++mt) {
                const int r = w * 32 + mt * 16 + lid;
                const int o = r * 64 + (((quad + 4 * ks) ^ (r & 7)) * 8);
                ah[mt]  = *(const bf16x8*)&As[o];
                al_[mt] = *(const bf16x8*)&As[PA_HALF + o];
            }
#pragma unroll
            for (int nt = 0; nt < 4; ++nt) {
                const int rn = nt * 16 + lid;
                const int o = rn * 64 + (((quad + 4 * ks) ^ (rn & 7)) * 8);
                bh[nt] = *(const bf16x8*)&Bs[o];
                bl[nt] = *(const bf16x8*)&Bs[PB_HALF + o];
            }
#pragma unroll
            for (int mt = 0; mt < 2; ++mt)
#pragma unroll
                for (int nt = 0; nt < 4; ++nt) {
                    acc[mt][nt] = __builtin_amdgcn_mfma_f32_16x16x32_bf16(ah[mt],  bh[nt], acc[mt][nt], 0, 0, 0);
                    acc[mt][nt] = __builtin_amdgcn_mfma_f32_16x16x32_bf16(ah[mt],  bl[nt], acc[mt][nt], 0, 0, 0);
                    acc[mt][nt] = __builtin_amdgcn_mfma_f32_16x16x32_bf16(al_[mt], bh[nt], acc[mt][nt], 0, 0, 0);
                }
        }
    }

    float bv[4];
#pragma unroll
    for (int nt = 0; nt < 4; ++nt)
        bv[nt] = bias[n0 + nt * 16 + lid];

#pragma unroll
    for (int mt = 0; mt < 2; ++mt)
#pragma unroll
        for (int nt = 0; nt < 4; ++nt) {
            const int col = n0 + nt * 16 + lid;
#pragma unroll
            for (int r = 0; r < 4; ++r) {
                const int row = m0 + w * 32 + mt * 16 + quad * 4 + r;
                const float val = acc[mt][nt][r] + bv[nt];
                const unsigned short h = f2bf_rne(val);
                const unsigned short l = f2bf_rne(val - bf2f(h));
                if (fragQ) {
                    const long long fa = qf_addr(row, col);
                    OH[fa] = h; OL[fa] = l;
                } else {
                    const long long off = (long long)row * DMODEL + col;
                    OH[off] = h; OL[off] = l;
                }
            }
        }
}

// ---------------------------------------------------------------------------
// fp32 tiled GEMM (still used for out proj).
// ---------------------------------------------------------------------------
__global__ __launch_bounds__(256) void gemm_bias_kernel(
    const float* __restrict__ A, long long sA,
    const float* __restrict__ W, long long sW,
    const float* __restrict__ bias,
    float* __restrict__ C, long long sC,
    int M, int N, int K)
{
    A += (long long)blockIdx.z * sA;
    W += (long long)blockIdx.z * sW;
    C += (long long)blockIdx.z * sC;
    const int n0 = blockIdx.x * 64;
    const int m0 = blockIdx.y * 64;

    __shared__ float As[16][68];
    __shared__ float Bs[16][68];

    const int tid = threadIdx.x;
    const int tm = (tid >> 4) << 2;
    const int tn = (tid & 15) << 2;
    const int arow = tid >> 2, ak = (tid & 3) << 2;
    const int brow = tid >> 4, bn = (tid & 15) << 2;

    float acc[4][4] = {};

    for (int k0 = 0; k0 < K; k0 += 16) {
        float4 av = *(const float4*)&A[(long long)(m0 + arow) * K + k0 + ak];
        float4 wv = *(const float4*)&W[(long long)(k0 + brow) * N + n0 + bn];
        As[ak + 0][arow] = av.x;
        As[ak + 1][arow] = av.y;
        As[ak + 2][arow] = av.z;
        As[ak + 3][arow] = av.w;
        *(float4*)&Bs[brow][bn] = wv;
        __syncthreads();
#pragma unroll
        for (int kk = 0; kk < 16; ++kk) {
            float4 a4 = *(const float4*)&As[kk][tm];
            float4 b4 = *(const float4*)&Bs[kk][tn];
            float aa[4] = {a4.x, a4.y, a4.z, a4.w};
            float bb[4] = {b4.x, b4.y, b4.z, b4.w};
#pragma unroll
            for (int i = 0; i < 4; ++i)
#pragma unroll
                for (int j = 0; j < 4; ++j)
                    acc[i][j] = fmaf(aa[i], bb[j], acc[i][j]);
        }
        __syncthreads();
    }

    float4 bv = make_float4(0.f, 0.f, 0.f, 0.f);
    if (bias) bv = *(const float4*)&bias[n0 + tn];
#pragma unroll
    for (int i = 0; i < 4; ++i) {
        float4 o = make_float4(acc[i][0] + bv.x, acc[i][1] + bv.y,
                               acc[i][2] + bv.z, acc[i][3] + bv.w);
        *(float4*)&C[(long long)(m0 + tm + i) * N + n0 + tn] = o;
    }
}

// ---------------------------------------------------------------------------
// Split-K fp32 GEMM: partials P[s][b*M+m][n] = A_b[m, kb:kb+kl] @ W_b[kb:kb+kl, n]
// ---------------------------------------------------------------------------
__global__ __launch_bounds__(256) void gemm_splitk_kernel(
    const float* __restrict__ A, long long sA,
    const float* __restrict__ W, long long sW,
    float* __restrict__ P,
    int M, int N, int K, int nsplit)
{
    const int nbatch = gridDim.z / nsplit;
    const int b = blockIdx.z / nsplit;
    const int s = blockIdx.z % nsplit;
    A += (long long)b * sA;
    W += (long long)b * sW;
    float* Pout = P + ((long long)s * nbatch + b) * M * N;

    const int n0 = blockIdx.x * 64;
    const int m0 = blockIdx.y * 64;
    const int kb = s * (K / nsplit);
    const int kl = K / nsplit;

    __shared__ float As[16][68];
    __shared__ float Bs[16][68];

    const int tid = threadIdx.x;
    const int tm = (tid >> 4) << 2;
    const int tn = (tid & 15) << 2;
    const int arow = tid >> 2, ak = (tid & 3) << 2;
    const int brow = tid >> 4, bn = (tid & 15) << 2;

    float acc[4][4] = {};

    for (int k0 = 0; k0 < kl; k0 += 16) {
        float4 av = *(const float4*)&A[(long long)(m0 + arow) * K + kb + k0 + ak];
        float4 wv = *(const float4*)&W[(long long)(kb + k0 + brow) * N + n0 + bn];
        As[ak + 0][arow] = av.x;
        As[ak + 1][arow] = av.y;
        As[ak + 2][arow] = av.z;
        As[ak + 3][arow] = av.w;
        *(float4*)&Bs[brow][bn] = wv;
        __syncthreads();
#pragma unroll
        for (int kk = 0; kk < 16; ++kk) {
            float4 a4 = *(const float4*)&As[kk][tm];
            float4 b4 = *(const float4*)&Bs[kk][tn];
            float aa[4] = {a4.x, a4.y, a4.z, a4.w};
            float bb[4] = {b4.x, b4.y, b4.z, b4.w};
#pragma unroll
            for (int i = 0; i < 4; ++i)
#pragma unroll
                for (int j = 0; j < 4; ++j)
                    acc[i][j] = fmaf(aa[i], bb[j], acc[i][j]);
        }
        __syncthreads();
    }

#pragma unroll
    for (int i = 0; i < 4; ++i) {
        float4 o = make_float4(acc[i][0], acc[i][1], acc[i][2], acc[i][3]);
        *(float4*)&Pout[(long long)(m0 + tm + i) * N + n0 + tn] = o;
    }
}

// C[i] = bias[i % N] + sum_s P[s*stride + i]   (vectorized, bias optional)
__global__ __launch_bounds__(256) void reduce_bias_kernel(
    const float* __restrict__ P, const float* __restrict__ bias,
    float* __restrict__ C, long long stride, int nsplit, int N)
{
    const long long i = ((long long)blockIdx.x * 256 + threadIdx.x) * 4;
    float4 s = *(const float4*)&P[i];
    for (int k = 1; k < nsplit; ++k) {
        float4 v = *(const float4*)&P[(long long)k * stride + i];
        s.x += v.x; s.y += v.y; s.z += v.z; s.w += v.w;
    }
    if (bias) {
        const int n = (int)(i % N);
        float4 b4 = *(const float4*)&bias[n];
        s.x += b4.x; s.y += b4.y; s.z += b4.z; s.w += b4.w;
    }
    *(float4*)&C[i] = s;
}

// ---------------------------------------------------------------------------
// Direct global->LDS staging of one 128-key x 64-d (hi+lo) K tile, 32 KB,
// by an 8-wave (512-thread) block.  Zero VGPRs hold staged data.
// Linear layout + 16B-slot XOR swizzle (physslot = slot ^ (row&7)).
// ---------------------------------------------------------------------------
#define HALF_USH 8192
#define TILE_USH 16384   // 32 KB

__device__ __forceinline__ void stage_issue(
    const unsigned short* __restrict__ Khi, const unsigned short* __restrict__ Klo,
    unsigned short* KsBuf, long long grow0, int h, int w, int lane)
{
    const int rsub = lane >> 3;            // row within 8-row chunk
    const int slot = (lane & 7) ^ rsub;    // logical 16B slot this lane fetches
#pragma unroll
    for (int it = 0; it < 4; ++it) {
        const int c = it * 8 + w;          // chunk 0..31 (wave-uniform), 1 KB each
        const int half = c >> 4;
        const int row  = (c & 15) * 8 + rsub;
        const unsigned short* src = half ? Klo : Khi;
        const unsigned short* g = &src[(grow0 + row) * DMODEL + h * 64 + slot * 8];
        __builtin_amdgcn_global_load_lds(
            (const __attribute__((address_space(1))) unsigned int*)g,
            (__attribute__((address_space(3))) unsigned int*)(KsBuf + c * 512),
            16, 0, 0);
    }
}

__device__ __forceinline__ f32x4 mfma3(bf16x8 ah, bf16x8 al, bf16x8 bh, bf16x8 bl, f32x4 s) {
    s = __builtin_amdgcn_mfma_f32_16x16x32_bf16(ah, bh, s, 0, 0, 0);
    s = __builtin_amdgcn_mfma_f32_16x16x32_bf16(ah, bl, s, 0, 0, 0);
    s = __builtin_amdgcn_mfma_f32_16x16x32_bf16(al, bh, s, 0, 0, 0);
    return s;
}

// ---------------------------------------------------------------------------
// Stats: partial row-sums of exp(QK^T/8) into lsum (atomicAdd, k-split=4).
// 512 threads: 8 waves x 32 q-rows (mt=2) -> Q-tile 256, 128-key K tiles.
// (R5 configuration -- best measured for this kernel.)
// ---------------------------------------------------------------------------
__global__ __launch_bounds__(512, 4) void attn_stats_kernel(
    const unsigned short* __restrict__ QfH, const unsigned short* __restrict__ QfL,
    const unsigned short* __restrict__ Khi, const unsigned short* __restrict__ Klo,
    float* __restrict__ lsum)
{
    const int q0 = blockIdx.x * 256;
    const int h  = blockIdx.y;
    const int b  = blockIdx.z >> 2;
    const int kbase = (blockIdx.z & 3) * (SEQ / KSPLIT);
    const int tid = threadIdx.x;
    const int w = tid >> 6, lane = tid & 63;
    const int quad = lane >> 4, lid = lane & 15;

    __shared__ unsigned short Ks[2 * TILE_USH];   // 64 KB, double buffer

    bf16x8 ah[2][2], al[2][2];
#pragma unroll
    for (int mt = 0; mt < 2; ++mt) {
        const long long qt = (long long)(b * SEQ + q0) / 16 + w * 2 + mt;
#pragma unroll
        for (int ks = 0; ks < 2; ++ks) {
            const long long fa = (((qt * NHEAD + h) * 8 + (quad + 4 * ks)) * 16 + lid) * 8;
            ah[mt][ks] = *(const bf16x8*)&QfH[fa];
            al[mt][ks] = *(const bf16x8*)&QfL[fa];
        }
    }

    float ls[2][4] = {};
    const long long grow0 = (long long)b * SEQ + kbase;

    stage_issue(Khi, Klo, Ks, grow0, h, w, lane);
    __syncthreads();                       // buf0 ready (vmcnt drain)

    for (int kc = 0; kc < SEQ / KSPLIT; kc += 128) {
        const int buf = (kc >> 7) & 1;
        if (kc + 128 < SEQ / KSPLIT)
            stage_issue(Khi, Klo, Ks + (buf ^ 1) * TILE_USH,
                        grow0 + kc + 128, h, w, lane);   // flies under compute
        const unsigned short* Kc = Ks + buf * TILE_USH;

#pragma unroll
        for (int kt = 0; kt < 8; ++kt) {
            const int rr = kt * 16 + lid;
            const int sw = rr & 7;
            bf16x8 bh[2], bl[2];
#pragma unroll
            for (int ks = 0; ks < 2; ++ks) {
                const int o = rr * 64 + (((quad + 4 * ks) ^ sw) * 8);
                bh[ks] = *(const bf16x8*)&Kc[o];
                bl[ks] = *(const bf16x8*)&Kc[HALF_USH + o];
            }
#pragma unroll
            for (int mt = 0; mt < 2; ++mt) {
                f32x4 s = {0.f, 0.f, 0.f, 0.f};
#pragma unroll
                for (int ks = 0; ks < 2; ++ks)
                    s = mfma3(ah[mt][ks], al[mt][ks], bh[ks], bl[ks], s);
#pragma unroll
                for (int r = 0; r < 4; ++r)
                    ls[mt][r] += __expf(s[r] * 0.125f);
            }
        }
        __syncthreads();                   // next buf loaded; cur free to overwrite
    }

#pragma unroll
    for (int off = 1; off < 16; off <<= 1)
#pragma unroll
        for (int mt = 0; mt < 2; ++mt)
#pragma unroll
            for (int r = 0; r < 4; ++r)
                ls[mt][r] += __shfl_xor(ls[mt][r], off);

    if (lid == 0) {
        const long long base = ((long long)(b * NHEAD + h)) * SEQ + q0 + w * 32 + quad * 4;
#pragma unroll
        for (int mt = 0; mt < 2; ++mt)
#pragma unroll
            for (int r = 0; r < 4; ++r)
                atomicAdd(&lsum[base + mt * 16 + r], ls[mt][r]);
    }
}

// lsum -> c = 1/(16*l)
__global__ __launch_bounds__(256) void recip_kernel(float* __restrict__ p) {
    const int i = blockIdx.x * 256 + threadIdx.x;
    p[i] = 0.0625f / p[i];
}

// ---------------------------------------------------------------------------
// Avg (R4 configuration -- best measured: 60.2 us): block owns 128x128
// (q,k) tile; loops 16 heads.  512 threads: 8 waves x 16 q-rows.
// Double-buffered direct-to-LDS staging; head h+1's loads fly under head
// h's compute.
// ---------------------------------------------------------------------------
__global__ __launch_bounds__(512, 4) void attn_avg_kernel(
    const unsigned short* __restrict__ QfH, const unsigned short* __restrict__ QfL,
    const unsigned short* __restrict__ Khi, const unsigned short* __restrict__ Klo,
    const float* __restrict__ cIn, float* __restrict__ avg)
{
    const int q0 = blockIdx.x * 128;
    const int k0 = blockIdx.y * 128;
    const int b  = blockIdx.z;
    const int tid = threadIdx.x;
    const int w = tid >> 6, lane = tid & 63;
    const int quad = lane >> 4, lid = lane & 15;

    __shared__ unsigned short Ks[2 * TILE_USH];   // 64 KB, double buffer

    f32x4 acc[8] = {};
    const long long grow0 = (long long)b * SEQ + k0;
    const long long qt = (long long)(b * SEQ + q0) / 16 + w;

    stage_issue(Khi, Klo, Ks, grow0, 0, w, lane);
    __syncthreads();                       // buf0 ready

    for (int h = 0; h < NHEAD; ++h) {
        bf16x8 ah[2], al[2];
        float c_[4];
#pragma unroll
        for (int ks = 0; ks < 2; ++ks) {
            const long long fa = (((qt * NHEAD + h) * 8 + (quad + 4 * ks)) * 16 + lid) * 8;
            ah[ks] = *(const bf16x8*)&QfH[fa];
            al[ks] = *(const bf16x8*)&QfL[fa];
        }
        const long long cb = ((long long)(b * NHEAD + h)) * SEQ + q0 + w * 16 + quad * 4;
#pragma unroll
        for (int r = 0; r < 4; ++r)
            c_[r] = cIn[cb + r];

        const int buf = h & 1;
        if (h + 1 < NHEAD)
            stage_issue(Khi, Klo, Ks + (buf ^ 1) * TILE_USH,
                        grow0, h + 1, w, lane);          // flies under compute
        const unsigned short* Kc = Ks + buf * TILE_USH;

#pragma unroll
        for (int kt = 0; kt < 8; ++kt) {
            const int rr = kt * 16 + lid;
            const int sw = rr & 7;
            bf16x8 bh[2], bl[2];
#pragma unroll
            for (int ks = 0; ks < 2; ++ks) {
                const int o = rr * 64 + (((quad + 4 * ks) ^ sw) * 8);
                bh[ks] = *(const bf16x8*)&Kc[o];
                bl[ks] = *(const bf16x8*)&Kc[HALF_USH + o];
            }
            f32x4 s = {0.f, 0.f, 0.f, 0.f};
#pragma unroll
            for (int ks = 0; ks < 2; ++ks)
                s = mfma3(ah[ks], al[ks], bh[ks], bl[ks], s);
#pragma unroll
            for (int r = 0; r < 4; ++r)
                acc[kt][r] = fmaf(__expf(s[r] * 0.125f), c_[r], acc[kt][r]);
        }
        __syncthreads();                   // next buf loaded; cur free
    }

#pragma unroll
    for (int kt = 0; kt < 8; ++kt)
#pragma unroll
        for (int r = 0; r < 4; ++r) {
            const int q = q0 + w * 16 + quad * 4 + r;
            avg[((long long)(b * SEQ + q)) * SEQ + k0 + kt * 16 + lid] = acc[kt][r];
        }
}

// ---------------------------------------------------------------------------
extern "C" void kernel_launch(void* const* d_in, const int* in_sizes, int n_in,
                              void* d_out, int out_size, void* d_ws, size_t ws_size,
                              hipStream_t stream)
{
    const float* query = (const float*)d_in[0];
    const float* key   = (const float*)d_in[1];
    const float* value = (const float*)d_in[2];
    const float* Wq    = (const float*)d_in[3];
    const float* bq    = (const float*)d_in[4];
    const float* Wk    = (const float*)d_in[5];
    const float* bk    = (const float*)d_in[6];
    const float* Wv    = (const float*)d_in[7];
    const float* bv    = (const float*)d_in[8];
    const float* Wo    = (const float*)d_in[9];
    const float* bo    = (const float*)d_in[10];

    float* out = (float*)d_out;                         // [B,S,DMODEL]
    float* avg = out + (long long)BATCH * SEQ * DMODEL; // [B,S,S]

    const long long QKN = (long long)MROWS * DMODEL;    // 4.2M elems
    unsigned short* QfH = (unsigned short*)d_ws;        // frag-major, 8 MB each
    unsigned short* QfL = QfH + QKN;
    unsigned short* Khi = QfL + QKN;                    // row-major
    unsigned short* Klo = Khi + QKN;
    unsigned short* AspH = Klo + QKN;                   // split input scratch (reused)
    unsigned short* AspL = AspH + QKN;
    unsigned short* WTh  = AspL + QKN;                  // W^T split, 2 MB each
    unsigned short* WTl  = WTh + (long long)DMODEL * DMODEL;
    float* Vb   = (float*)(WTl + (long long)DMODEL * DMODEL); // 4096x64 fp32
    float* lBuf = Vb + (long long)MROWS * DK;                 // B*H*S
    float* ao   = lBuf + (long long)BATCH * NHEAD * SEQ;      // 4096x64

    // Dead-region reuse for split-K partials (in-stream ordering guarantees):
    //  - V proj partials (16 x 1 MB) live in AspH..AspL (dead after proj_mfma(K)).
    //  - avg@V partials (32 x 1 MB) live in QfH..Klo (dead after attn_avg).
    float* Pv  = (float*)AspH;
    float* Pav = (float*)QfH;

    dim3 blk(256);
    hipMemsetAsync(lBuf, 0, (size_t)BATCH * NHEAD * SEQ * sizeof(float), stream);

    const int convGrid = (int)(QKN / (256 * 4));        // 4096
    dim3 tGrid(DMODEL / 64, DMODEL / 64);               // 16x16
    dim3 pGrid(DMODEL / 64, MROWS / 128);               // 16x32 = 512 blocks

    // Q projection (MFMA split-bf16), emits fragment-major Q hi/lo.
    conv_split_kernel<<<convGrid, blk, 0, stream>>>(query, AspH, AspL);
    conv_splitT_kernel<<<tGrid, blk, 0, stream>>>(Wq, WTh, WTl);
    proj_mfma_kernel<<<pGrid, blk, 0, stream>>>(AspH, AspL, WTh, WTl, bq, QfH, QfL, 1);

    // K projection (MFMA split-bf16), emits row-major K hi/lo.  Scratch reused.
    conv_split_kernel<<<convGrid, blk, 0, stream>>>(key, AspH, AspL);
    conv_splitT_kernel<<<tGrid, blk, 0, stream>>>(Wk, WTh, WTl);
    proj_mfma_kernel<<<pGrid, blk, 0, stream>>>(AspH, AspL, WTh, WTl, bk, Khi, Klo, 0);

    // V projection: split-K fp32 (16 splits -> 1024 blocks), then reduce+bias.
    gemm_splitk_kernel<<<dim3(DK / 64, MROWS / 64, 16), blk, 0, stream>>>(
        value, 0, Wv, 0, Pv, MROWS, DK, DMODEL, 16);
    reduce_bias_kernel<<<dim3((int)((long long)MROWS * DK / 1024)), blk, 0, stream>>>(
        Pv, bv, Vb, (long long)MROWS * DK, 16, DK);

    // Softmax denominators (k-split partial sums), then reciprocal.
    attn_stats_kernel<<<dim3(SEQ / 256, NHEAD, BATCH * KSPLIT), dim3(512), 0, stream>>>(
        QfH, QfL, Khi, Klo, lBuf);
    recip_kernel<<<dim3(BATCH * NHEAD * SEQ / 256), blk, 0, stream>>>(lBuf);

    // Head-averaged attention matrix.
    attn_avg_kernel<<<dim3(SEQ / 128, SEQ / 128, BATCH), dim3(512), 0, stream>>>(
        QfH, QfL, Khi, Klo, lBuf, avg);

    // attn_output = avg_attn @ V: split-K fp32 (32 splits x 2 batches -> 2048
    // blocks) into dead Qf/K region, then reduce (no bias).
    gemm_splitk_kernel<<<dim3(DK / 64, SEQ / 64, BATCH * 32), blk, 0, stream>>>(
        avg, (long long)SEQ * SEQ, Vb, (long long)SEQ * DK, Pav, SEQ, DK, SEQ, 32);
    reduce_bias_kernel<<<dim3((int)((long long)MROWS * DK / 1024)), blk, 0, stream>>>(
        Pav, nullptr, ao, (long long)MROWS * DK, 32, DK);

    // output = attn_output @ Wo + bo
    gemm_bias_kernel<<<dim3(DMODEL / 64, MROWS / 64, 1), blk, 0, stream>>>(
        ao, 0, Wo, 0, bo, out, 0, MROWS, DMODEL, DK);
}

// Round 9
// 357.622 us; speedup vs baseline: 1.1496x; 1.0041x over previous
//
#include <hip/hip_runtime.h>

// Problem constants
#define BATCH 2
#define SEQ   2048
#define DMODEL 1024
#define NHEAD 16
#define DK    64
#define MROWS (BATCH * SEQ)   // 4096
#define KSPLIT 4

using bf16x8 = __attribute__((ext_vector_type(8))) short;  // 8 bf16 (4 VGPRs)
using f32x4  = __attribute__((ext_vector_type(4))) float;  // MFMA C/D

__device__ __forceinline__ unsigned short f2bf_rne(float x) {
    unsigned u = __float_as_uint(x);
    u += 0x7FFFu + ((u >> 16) & 1u);
    return (unsigned short)(u >> 16);
}
__device__ __forceinline__ float bf2f(unsigned short h) {
    return __uint_as_float((unsigned)h << 16);
}

// Fragment-major layout for the MFMA A operand (Q), indexed by GLOBAL row.
__device__ __forceinline__ long long qf_addr(int row, int d) {
    const int qt = row >> 4, lid = row & 15;
    const int hh = d >> 6, ch = (d >> 3) & 7, j = d & 7;
    return ((((long long)qt * NHEAD + hh) * 8 + ch) * 16 + lid) * 8 + j;
}

// ---------------------------------------------------------------------------
// Elementwise split fp32 -> (hi, lo) bf16.  n must be /1024.
// ---------------------------------------------------------------------------
__global__ __launch_bounds__(256) void conv_split_kernel(
    const float* __restrict__ x, unsigned short* __restrict__ hi,
    unsigned short* __restrict__ lo)
{
    const long long i = ((long long)blockIdx.x * 256 + threadIdx.x) * 4;
    float4 v = *(const float4*)&x[i];
    ushort4 h4, l4;
    unsigned short h;
    h = f2bf_rne(v.x); h4.x = h; l4.x = f2bf_rne(v.x - bf2f(h));
    h = f2bf_rne(v.y); h4.y = h; l4.y = f2bf_rne(v.y - bf2f(h));
    h = f2bf_rne(v.z); h4.z = h; l4.z = f2bf_rne(v.z - bf2f(h));
    h = f2bf_rne(v.w); h4.w = h; l4.w = f2bf_rne(v.w - bf2f(h));
    *(ushort4*)&hi[i] = h4;
    *(ushort4*)&lo[i] = l4;
}

// ---------------------------------------------------------------------------
// Transpose + split: W[K=1024][N=1024] fp32 -> WT hi/lo [N][K] bf16.
// 64x64 tile per block via LDS.
// ---------------------------------------------------------------------------
__global__ __launch_bounds__(256) void conv_splitT_kernel(
    const float* __restrict__ W, unsigned short* __restrict__ hiT,
    unsigned short* __restrict__ loT)
{
    const int k0 = blockIdx.y * 64;
    const int n0 = blockIdx.x * 64;
    const int tid = threadIdx.x;
    __shared__ float T[64][68];
#pragma unroll
    for (int it = 0; it < 4; ++it) {
        const int r = it * 16 + (tid >> 4);
        const int c = (tid & 15) * 4;
        float4 v = *(const float4*)&W[(long long)(k0 + r) * DMODEL + n0 + c];
        T[r][c] = v.x; T[r][c + 1] = v.y; T[r][c + 2] = v.z; T[r][c + 3] = v.w;
    }
    __syncthreads();
#pragma unroll
    for (int it = 0; it < 4; ++it) {
        const int n = it * 16 + (tid >> 4);
        const int kc = (tid & 15) * 4;
        ushort4 h4, l4;
        float v; unsigned short h;
        v = T[kc + 0][n]; h = f2bf_rne(v); h4.x = h; l4.x = f2bf_rne(v - bf2f(h));
        v = T[kc + 1][n]; h = f2bf_rne(v); h4.y = h; l4.y = f2bf_rne(v - bf2f(h));
        v = T[kc + 2][n]; h = f2bf_rne(v); h4.z = h; l4.z = f2bf_rne(v - bf2f(h));
        v = T[kc + 3][n]; h = f2bf_rne(v); h4.w = h; l4.w = f2bf_rne(v - bf2f(h));
        const long long off = (long long)(n0 + n) * DMODEL + k0 + kc;
        *(ushort4*)&hiT[off] = h4;
        *(ushort4*)&loT[off] = l4;
    }
}

// ---------------------------------------------------------------------------
// Split-bf16 MFMA projection GEMM v2: C = A @ W + bias, M=4096, N=K=1024.
// 64n x 128m tiles -> grid 16x32 = 512 blocks (2/CU).  BK=64.  Staging via
// global_load_lds into linear [rows][64] hi/lo tiles with the 16B-slot XOR
// swizzle (physslot = slot ^ (row&7)).  fp32 accumulation chain order
// identical to v1 -> bit-identical output.
// ---------------------------------------------------------------------------
#define PA_HALF 8192    // ushorts: 128 rows x 64
#define PA_TILE 16384   // 32 KB
#define PB_HALF 4096    // 64 rows x 64
#define PB_TILE 8192    // 16 KB

__global__ __launch_bounds__(256, 2) void proj_mfma_kernel(
    const unsigned short* __restrict__ AH, const unsigned short* __restrict__ AL,
    const unsigned short* __restrict__ BTH, const unsigned short* __restrict__ BTL,
    const float* __restrict__ bias,
    unsigned short* __restrict__ OH, unsigned short* __restrict__ OL, int fragQ)
{
    const int n0 = blockIdx.x * 64;
    const int m0 = blockIdx.y * 128;
    const int tid = threadIdx.x;
    const int w = tid >> 6, lane = tid & 63;
    const int quad = lane >> 4, lid = lane & 15;
    const int rsub = lane >> 3;            // row within 8-row chunk
    const int slot = (lane & 7) ^ rsub;    // logical 16B slot this lane fetches

    __shared__ unsigned short As[PA_TILE];   // 32 KB (hi ++ lo)
    __shared__ unsigned short Bs[PB_TILE];   // 16 KB (hi ++ lo)

    f32x4 acc[2][4] = {};   // wave w owns m rows w*32..w*32+31; all 64 n cols

    for (int kc = 0; kc < DMODEL; kc += 64) {
        __syncthreads();                   // previous compute done, LDS free
        // Stage A-tile: 32 chunks (16 hi + 16 lo) of 8 rows x 128 B.
#pragma unroll
        for (int it = 0; it < 8; ++it) {
            const int c = it * 4 + w;
            const int half = c >> 4;
            const int row  = (c & 15) * 8 + rsub;
            const unsigned short* src = half ? AL : AH;
            const unsigned short* g = &src[(long long)(m0 + row) * DMODEL + kc + slot * 8];
            __builtin_amdgcn_global_load_lds(
                (const __attribute__((address_space(1))) unsigned int*)g,
                (__attribute__((address_space(3))) unsigned int*)(As + c * 512),
                16, 0, 0);
        }
        // Stage B-tile: 16 chunks (8 hi + 8 lo).
#pragma unroll
        for (int it = 0; it < 4; ++it) {
            const int c = it * 4 + w;
            const int half = c >> 3;
            const int row  = (c & 7) * 8 + rsub;
            const unsigned short* src = half ? BTL : BTH;
            const unsigned short* g = &src[(long long)(n0 + row) * DMODEL + kc + slot * 8];
            __builtin_amdgcn_global_load_lds(
                (const __attribute__((address_space(1))) unsigned int*)g,
                (__attribute__((address_space(3))) unsigned int*)(Bs + c * 512),
                16, 0, 0);
        }
        __syncthreads();                   // drains loads; tile ready

#pragma unroll
        for (int ks = 0; ks < 2; ++ks) {   // two 32-k sub-chunks, in k order
            bf16x8 ah[2], al_[2], bh[4], bl[4];
#pragma unroll
            for (int mt = 0; mt < 2; ++mt) {
                const int r = w * 32 + mt * 16 + lid;
                const int o = r * 64 + (((quad + 4 * ks) ^ (r & 7)) * 8);
                ah[mt]  = *(const bf16x8*)&As[o];
                al_[mt] = *(const bf16x8*)&As[PA_HALF + o];
            }
#pragma unroll
            for (int nt = 0; nt < 4; ++nt) {
                const int rn = nt * 16 + lid;
                const int o = rn * 64 + (((quad + 4 * ks) ^ (rn & 7)) * 8);
                bh[nt] = *(const bf16x8*)&Bs[o];
                bl[nt] = *(const bf16x8*)&Bs[PB_HALF + o];
            }
#pragma unroll
            for (int mt = 0; mt < 2; ++mt)
#pragma unroll
                for (int nt = 0; nt < 4; ++nt) {
                    acc[mt][nt] = __builtin_amdgcn_mfma_f32_16x16x32_bf16(ah[mt],  bh[nt], acc[mt][nt], 0, 0, 0);
                    acc[mt][nt] = __builtin_amdgcn_mfma_f32_16x16x32_bf16(ah[mt],  bl[nt], acc[mt][nt], 0, 0, 0);
                    acc[mt][nt] = __builtin_amdgcn_mfma_f32_16x16x32_bf16(al_[mt], bh[nt], acc[mt][nt], 0, 0, 0);
                }
        }
    }

    float bv[4];
#pragma unroll
    for (int nt = 0; nt < 4; ++nt)
        bv[nt] = bias[n0 + nt * 16 + lid];

#pragma unroll
    for (int mt = 0; mt < 2; ++mt)
#pragma unroll
        for (int nt = 0; nt < 4; ++nt) {
            const int col = n0 + nt * 16 + lid;
#pragma unroll
            for (int r = 0; r < 4; ++r) {
                const int row = m0 + w * 32 + mt * 16 + quad * 4 + r;
                const float val = acc[mt][nt][r] + bv[nt];
                const unsigned short h = f2bf_rne(val);
                const unsigned short l = f2bf_rne(val - bf2f(h));
                if (fragQ) {
                    const long long fa = qf_addr(row, col);
                    OH[fa] = h; OL[fa] = l;
                } else {
                    const long long off = (long long)row * DMODEL + col;
                    OH[off] = h; OL[off] = l;
                }
            }
        }
}

// ---------------------------------------------------------------------------
// fp32 tiled GEMM (still used for out proj).
// ---------------------------------------------------------------------------
__global__ __launch_bounds__(256) void gemm_bias_kernel(
    const float* __restrict__ A, long long sA,
    const float* __restrict__ W, long long sW,
    const float* __restrict__ bias,
    float* __restrict__ C, long long sC,
    int M, int N, int K)
{
    A += (long long)blockIdx.z * sA;
    W += (long long)blockIdx.z * sW;
    C += (long long)blockIdx.z * sC;
    const int n0 = blockIdx.x * 64;
    const int m0 = blockIdx.y * 64;

    __shared__ float As[16][68];
    __shared__ float Bs[16][68];

    const int tid = threadIdx.x;
    const int tm = (tid >> 4) << 2;
    const int tn = (tid & 15) << 2;
    const int arow = tid >> 2, ak = (tid & 3) << 2;
    const int brow = tid >> 4, bn = (tid & 15) << 2;

    float acc[4][4] = {};

    for (int k0 = 0; k0 < K; k0 += 16) {
        float4 av = *(const float4*)&A[(long long)(m0 + arow) * K + k0 + ak];
        float4 wv = *(const float4*)&W[(long long)(k0 + brow) * N + n0 + bn];
        As[ak + 0][arow] = av.x;
        As[ak + 1][arow] = av.y;
        As[ak + 2][arow] = av.z;
        As[ak + 3][arow] = av.w;
        *(float4*)&Bs[brow][bn] = wv;
        __syncthreads();
#pragma unroll
        for (int kk = 0; kk < 16; ++kk) {
            float4 a4 = *(const float4*)&As[kk][tm];
            float4 b4 = *(const float4*)&Bs[kk][tn];
            float aa[4] = {a4.x, a4.y, a4.z, a4.w};
            float bb[4] = {b4.x, b4.y, b4.z, b4.w};
#pragma unroll
            for (int i = 0; i < 4; ++i)
#pragma unroll
                for (int j = 0; j < 4; ++j)
                    acc[i][j] = fmaf(aa[i], bb[j], acc[i][j]);
        }
        __syncthreads();
    }

    float4 bv = make_float4(0.f, 0.f, 0.f, 0.f);
    if (bias) bv = *(const float4*)&bias[n0 + tn];
#pragma unroll
    for (int i = 0; i < 4; ++i) {
        float4 o = make_float4(acc[i][0] + bv.x, acc[i][1] + bv.y,
                               acc[i][2] + bv.z, acc[i][3] + bv.w);
        *(float4*)&C[(long long)(m0 + tm + i) * N + n0 + tn] = o;
    }
}

// ---------------------------------------------------------------------------
// Split-K fp32 GEMM: partials P[s][b*M+m][n] = A_b[m, kb:kb+kl] @ W_b[kb:kb+kl, n]
// ---------------------------------------------------------------------------
__global__ __launch_bounds__(256) void gemm_splitk_kernel(
    const float* __restrict__ A, long long sA,
    const float* __restrict__ W, long long sW,
    float* __restrict__ P,
    int M, int N, int K, int nsplit)
{
    const int nbatch = gridDim.z / nsplit;
    const int b = blockIdx.z / nsplit;
    const int s = blockIdx.z % nsplit;
    A += (long long)b * sA;
    W += (long long)b * sW;
    float* Pout = P + ((long long)s * nbatch + b) * M * N;

    const int n0 = blockIdx.x * 64;
    const int m0 = blockIdx.y * 64;
    const int kb = s * (K / nsplit);
    const int kl = K / nsplit;

    __shared__ float As[16][68];
    __shared__ float Bs[16][68];

    const int tid = threadIdx.x;
    const int tm = (tid >> 4) << 2;
    const int tn = (tid & 15) << 2;
    const int arow = tid >> 2, ak = (tid & 3) << 2;
    const int brow = tid >> 4, bn = (tid & 15) << 2;

    float acc[4][4] = {};

    for (int k0 = 0; k0 < kl; k0 += 16) {
        float4 av = *(const float4*)&A[(long long)(m0 + arow) * K + kb + k0 + ak];
        float4 wv = *(const float4*)&W[(long long)(kb + k0 + brow) * N + n0 + bn];
        As[ak + 0][arow] = av.x;
        As[ak + 1][arow] = av.y;
        As[ak + 2][arow] = av.z;
        As[ak + 3][arow] = av.w;
        *(float4*)&Bs[brow][bn] = wv;
        __syncthreads();
#pragma unroll
        for (int kk = 0; kk < 16; ++kk) {
            float4 a4 = *(const float4*)&As[kk][tm];
            float4 b4 = *(const float4*)&Bs[kk][tn];
            float aa[4] = {a4.x, a4.y, a4.z, a4.w};
            float bb[4] = {b4.x, b4.y, b4.z, b4.w};
#pragma unroll
            for (int i = 0; i < 4; ++i)
#pragma unroll
                for (int j = 0; j < 4; ++j)
                    acc[i][j] = fmaf(aa[i], bb[j], acc[i][j]);
        }
        __syncthreads();
    }

#pragma unroll
    for (int i = 0; i < 4; ++i) {
        float4 o = make_float4(acc[i][0], acc[i][1], acc[i][2], acc[i][3]);
        *(float4*)&Pout[(long long)(m0 + tm + i) * N + n0 + tn] = o;
    }
}

// C[i] = bias[i % N] + sum_s P[s*stride + i]   (vectorized, bias optional)
__global__ __launch_bounds__(256) void reduce_bias_kernel(
    const float* __restrict__ P, const float* __restrict__ bias,
    float* __restrict__ C, long long stride, int nsplit, int N)
{
    const long long i = ((long long)blockIdx.x * 256 + threadIdx.x) * 4;
    float4 s = *(const float4*)&P[i];
    for (int k = 1; k < nsplit; ++k) {
        float4 v = *(const float4*)&P[(long long)k * stride + i];
        s.x += v.x; s.y += v.y; s.z += v.z; s.w += v.w;
    }
    if (bias) {
        const int n = (int)(i % N);
        float4 b4 = *(const float4*)&bias[n];
        s.x += b4.x; s.y += b4.y; s.z += b4.z; s.w += b4.w;
    }
    *(float4*)&C[i] = s;
}

// ---------------------------------------------------------------------------
// Direct global->LDS staging of one 128-key x 64-d (hi+lo) K tile, 32 KB,
// by an 8-wave (512-thread) block.  Zero VGPRs hold staged data.
// Linear layout + 16B-slot XOR swizzle (physslot = slot ^ (row&7)).
// ---------------------------------------------------------------------------
#define HALF_USH 8192
#define TILE_USH 16384   // 32 KB

__device__ __forceinline__ void stage_issue(
    const unsigned short* __restrict__ Khi, const unsigned short* __restrict__ Klo,
    unsigned short* KsBuf, long long grow0, int h, int w, int lane)
{
    const int rsub = lane >> 3;            // row within 8-row chunk
    const int slot = (lane & 7) ^ rsub;    // logical 16B slot this lane fetches
#pragma unroll
    for (int it = 0; it < 4; ++it) {
        const int c = it * 8 + w;          // chunk 0..31 (wave-uniform), 1 KB each
        const int half = c >> 4;
        const int row  = (c & 15) * 8 + rsub;
        const unsigned short* src = half ? Klo : Khi;
        const unsigned short* g = &src[(grow0 + row) * DMODEL + h * 64 + slot * 8];
        __builtin_amdgcn_global_load_lds(
            (const __attribute__((address_space(1))) unsigned int*)g,
            (__attribute__((address_space(3))) unsigned int*)(KsBuf + c * 512),
            16, 0, 0);
    }
}

__device__ __forceinline__ f32x4 mfma3(bf16x8 ah, bf16x8 al, bf16x8 bh, bf16x8 bl, f32x4 s) {
    s = __builtin_amdgcn_mfma_f32_16x16x32_bf16(ah, bh, s, 0, 0, 0);
    s = __builtin_amdgcn_mfma_f32_16x16x32_bf16(ah, bl, s, 0, 0, 0);
    s = __builtin_amdgcn_mfma_f32_16x16x32_bf16(al, bh, s, 0, 0, 0);
    return s;
}

// ---------------------------------------------------------------------------
// Stats: partial row-sums of exp(QK^T/8) into lsum (atomicAdd, k-split=4).
// 512 threads: 8 waves x 32 q-rows (mt=2) -> Q-tile 256, 128-key K tiles.
// XCD-chunked work swizzle (1024 blocks, %8==0): same-z (b,kbase) work
// co-locates on one XCD so K panels are served from local L2.
// ---------------------------------------------------------------------------
__global__ __launch_bounds__(512, 4) void attn_stats_kernel(
    const unsigned short* __restrict__ QfH, const unsigned short* __restrict__ QfL,
    const unsigned short* __restrict__ Khi, const unsigned short* __restrict__ Klo,
    float* __restrict__ lsum)
{
    int lin = blockIdx.x + 8 * (blockIdx.y + 16 * blockIdx.z);   // 1024 blocks
    lin = (lin & 7) * 128 + (lin >> 3);                          // bijective
    const int q0 = (lin & 7) * 256;
    const int h  = (lin >> 3) & 15;
    const int zz = lin >> 7;
    const int b  = zz >> 2;
    const int kbase = (zz & 3) * (SEQ / KSPLIT);
    const int tid = threadIdx.x;
    const int w = tid >> 6, lane = tid & 63;
    const int quad = lane >> 4, lid = lane & 15;

    __shared__ unsigned short Ks[2 * TILE_USH];   // 64 KB, double buffer

    bf16x8 ah[2][2], al[2][2];
#pragma unroll
    for (int mt = 0; mt < 2; ++mt) {
        const long long qt = (long long)(b * SEQ + q0) / 16 + w * 2 + mt;
#pragma unroll
        for (int ks = 0; ks < 2; ++ks) {
            const long long fa = (((qt * NHEAD + h) * 8 + (quad + 4 * ks)) * 16 + lid) * 8;
            ah[mt][ks] = *(const bf16x8*)&QfH[fa];
            al[mt][ks] = *(const bf16x8*)&QfL[fa];
        }
    }

    float ls[2][4] = {};
    const long long grow0 = (long long)b * SEQ + kbase;

    stage_issue(Khi, Klo, Ks, grow0, h, w, lane);
    __syncthreads();                       // buf0 ready (vmcnt drain)

    for (int kc = 0; kc < SEQ / KSPLIT; kc += 128) {
        const int buf = (kc >> 7) & 1;
        if (kc + 128 < SEQ / KSPLIT)
            stage_issue(Khi, Klo, Ks + (buf ^ 1) * TILE_USH,
                        grow0 + kc + 128, h, w, lane);   // flies under compute
        const unsigned short* Kc = Ks + buf * TILE_USH;

#pragma unroll
        for (int kt = 0; kt < 8; ++kt) {
            const int rr = kt * 16 + lid;
            const int sw = rr & 7;
            bf16x8 bh[2], bl[2];
#pragma unroll
            for (int ks = 0; ks < 2; ++ks) {
                const int o = rr * 64 + (((quad + 4 * ks) ^ sw) * 8);
                bh[ks] = *(const bf16x8*)&Kc[o];
                bl[ks] = *(const bf16x8*)&Kc[HALF_USH + o];
            }
#pragma unroll
            for (int mt = 0; mt < 2; ++mt) {
                f32x4 s = {0.f, 0.f, 0.f, 0.f};
                __builtin_amdgcn_s_setprio(1);
#pragma unroll
                for (int ks = 0; ks < 2; ++ks)
                    s = mfma3(ah[mt][ks], al[mt][ks], bh[ks], bl[ks], s);
                __builtin_amdgcn_s_setprio(0);
#pragma unroll
                for (int r = 0; r < 4; ++r)
                    ls[mt][r] += __expf(s[r] * 0.125f);
            }
        }
        __syncthreads();                   // next buf loaded; cur free to overwrite
    }

#pragma unroll
    for (int off = 1; off < 16; off <<= 1)
#pragma unroll
        for (int mt = 0; mt < 2; ++mt)
#pragma unroll
            for (int r = 0; r < 4; ++r)
                ls[mt][r] += __shfl_xor(ls[mt][r], off);

    if (lid == 0) {
        const long long base = ((long long)(b * NHEAD + h)) * SEQ + q0 + w * 32 + quad * 4;
#pragma unroll
        for (int mt = 0; mt < 2; ++mt)
#pragma unroll
            for (int r = 0; r < 4; ++r)
                atomicAdd(&lsum[base + mt * 16 + r], ls[mt][r]);
    }
}

// ---------------------------------------------------------------------------
// Avg: block owns 128x128 (q,k) tile; loops 16 heads; 8 waves x 16 q-rows
// (R4 geometry, best measured).  Additions:
//  - XCD-chunked work swizzle (512 blocks): the 16 q-blocks sharing a K
//    panel co-locate on one XCD -> stage loads hit local L2.
//  - Q-fragment register double-buffer: head h+1's Qf/lsum loads issued
//    under head h's compute (removes the per-head L2 serial chain).
//  - setprio(1) around the MFMA cluster (T5).
//  - recip fused: c = 0.0625f/lsum (identical IEEE division; recip kernel
//    dropped).
// ---------------------------------------------------------------------------
__global__ __launch_bounds__(512, 4) void attn_avg_kernel(
    const unsigned short* __restrict__ QfH, const unsigned short* __restrict__ QfL,
    const unsigned short* __restrict__ Khi, const unsigned short* __restrict__ Klo,
    const float* __restrict__ lsum, float* __restrict__ avg)
{
    int lin = blockIdx.x + 16 * (blockIdx.y + 16 * blockIdx.z);  // 512 blocks
    lin = (lin & 7) * 64 + (lin >> 3);                           // bijective
    const int q0 = (lin & 15) * 128;
    const int k0 = ((lin >> 4) & 15) * 128;
    const int b  = lin >> 8;
    const int tid = threadIdx.x;
    const int w = tid >> 6, lane = tid & 63;
    const int quad = lane >> 4, lid = lane & 15;

    __shared__ unsigned short Ks[2 * TILE_USH];   // 64 KB, double buffer

    f32x4 acc[8] = {};
    const long long grow0 = (long long)b * SEQ + k0;
    const long long qt = (long long)(b * SEQ + q0) / 16 + w;
    const long long cb0 = ((long long)b * NHEAD) * SEQ + q0 + w * 16 + quad * 4;

    // Q/lsum for head 0 (prologue).
    bf16x8 ahC[2], alC[2];
    float cC[4];
#pragma unroll
    for (int ks = 0; ks < 2; ++ks) {
        const long long fa = (((qt * NHEAD + 0) * 8 + (quad + 4 * ks)) * 16 + lid) * 8;
        ahC[ks] = *(const bf16x8*)&QfH[fa];
        alC[ks] = *(const bf16x8*)&QfL[fa];
    }
#pragma unroll
    for (int r = 0; r < 4; ++r)
        cC[r] = 0.0625f / lsum[cb0 + r];

    stage_issue(Khi, Klo, Ks, grow0, 0, w, lane);
    __syncthreads();                       // buf0 ready

    for (int h = 0; h < NHEAD; ++h) {
        const int buf = h & 1;
        if (h + 1 < NHEAD)
            stage_issue(Khi, Klo, Ks + (buf ^ 1) * TILE_USH,
                        grow0, h + 1, w, lane);          // K flies under compute

        // Prefetch Q/lsum for head h+1 (flies under compute; consumed after
        // the barrier via the register swap below).
        bf16x8 ahN[2], alN[2];
        float cN[4];
        if (h + 1 < NHEAD) {
#pragma unroll
            for (int ks = 0; ks < 2; ++ks) {
                const long long fa = (((qt * NHEAD + (h + 1)) * 8 + (quad + 4 * ks)) * 16 + lid) * 8;
                ahN[ks] = *(const bf16x8*)&QfH[fa];
                alN[ks] = *(const bf16x8*)&QfL[fa];
            }
#pragma unroll
            for (int r = 0; r < 4; ++r)
                cN[r] = 0.0625f / lsum[cb0 + (long long)(h + 1) * SEQ + r];
        }

        const unsigned short* Kc = Ks + buf * TILE_USH;

#pragma unroll
        for (int kt = 0; kt < 8; ++kt) {
            const int rr = kt * 16 + lid;
            const int sw = rr & 7;
            bf16x8 bh[2], bl[2];
#pragma unroll
            for (int ks = 0; ks < 2; ++ks) {
                const int o = rr * 64 + (((quad + 4 * ks) ^ sw) * 8);
                bh[ks] = *(const bf16x8*)&Kc[o];
                bl[ks] = *(const bf16x8*)&Kc[HALF_USH + o];
            }
            f32x4 s = {0.f, 0.f, 0.f, 0.f};
            __builtin_amdgcn_s_setprio(1);
#pragma unroll
            for (int ks = 0; ks < 2; ++ks)
                s = mfma3(ahC[ks], alC[ks], bh[ks], bl[ks], s);
            __builtin_amdgcn_s_setprio(0);
#pragma unroll
            for (int r = 0; r < 4; ++r)
                acc[kt][r] = fmaf(__expf(s[r] * 0.125f), cC[r], acc[kt][r]);
        }
        __syncthreads();                   // next buf loaded; cur free

        // Swap prefetched head state into current (register moves).
        if (h + 1 < NHEAD) {
#pragma unroll
            for (int ks = 0; ks < 2; ++ks) { ahC[ks] = ahN[ks]; alC[ks] = alN[ks]; }
#pragma unroll
            for (int r = 0; r < 4; ++r) cC[r] = cN[r];
        }
    }

#pragma unroll
    for (int kt = 0; kt < 8; ++kt)
#pragma unroll
        for (int r = 0; r < 4; ++r) {
            const int q = q0 + w * 16 + quad * 4 + r;
            avg[((long long)(b * SEQ + q)) * SEQ + k0 + kt * 16 + lid] = acc[kt][r];
        }
}

// ---------------------------------------------------------------------------
extern "C" void kernel_launch(void* const* d_in, const int* in_sizes, int n_in,
                              void* d_out, int out_size, void* d_ws, size_t ws_size,
                              hipStream_t stream)
{
    const float* query = (const float*)d_in[0];
    const float* key   = (const float*)d_in[1];
    const float* value = (const float*)d_in[2];
    const float* Wq    = (const float*)d_in[3];
    const float* bq    = (const float*)d_in[4];
    const float* Wk    = (const float*)d_in[5];
    const float* bk    = (const float*)d_in[6];
    const float* Wv    = (const float*)d_in[7];
    const float* bv    = (const float*)d_in[8];
    const float* Wo    = (const float*)d_in[9];
    const float* bo    = (const float*)d_in[10];

    float* out = (float*)d_out;                         // [B,S,DMODEL]
    float* avg = out + (long long)BATCH * SEQ * DMODEL; // [B,S,S]

    const long long QKN = (long long)MROWS * DMODEL;    // 4.2M elems
    unsigned short* QfH = (unsigned short*)d_ws;        // frag-major, 8 MB each
    unsigned short* QfL = QfH + QKN;
    unsigned short* Khi = QfL + QKN;                    // row-major
    unsigned short* Klo = Khi + QKN;
    unsigned short* AspH = Klo + QKN;                   // split input scratch (reused)
    unsigned short* AspL = AspH + QKN;
    unsigned short* WTh  = AspL + QKN;                  // W^T split, 2 MB each
    unsigned short* WTl  = WTh + (long long)DMODEL * DMODEL;
    float* Vb   = (float*)(WTl + (long long)DMODEL * DMODEL); // 4096x64 fp32
    float* lBuf = Vb + (long long)MROWS * DK;                 // B*H*S
    float* ao   = lBuf + (long long)BATCH * NHEAD * SEQ;      // 4096x64

    // Dead-region reuse for split-K partials (in-stream ordering guarantees):
    //  - V proj partials (16 x 1 MB) live in AspH..AspL (dead after proj_mfma(K)).
    //  - avg@V partials (32 x 1 MB) live in QfH..Klo (dead after attn_avg).
    float* Pv  = (float*)AspH;
    float* Pav = (float*)QfH;

    dim3 blk(256);
    hipMemsetAsync(lBuf, 0, (size_t)BATCH * NHEAD * SEQ * sizeof(float), stream);

    const int convGrid = (int)(QKN / (256 * 4));        // 4096
    dim3 tGrid(DMODEL / 64, DMODEL / 64);               // 16x16
    dim3 pGrid(DMODEL / 64, MROWS / 128);               // 16x32 = 512 blocks

    // Q projection (MFMA split-bf16), emits fragment-major Q hi/lo.
    conv_split_kernel<<<convGrid, blk, 0, stream>>>(query, AspH, AspL);
    conv_splitT_kernel<<<tGrid, blk, 0, stream>>>(Wq, WTh, WTl);
    proj_mfma_kernel<<<pGrid, blk, 0, stream>>>(AspH, AspL, WTh, WTl, bq, QfH, QfL, 1);

    // K projection (MFMA split-bf16), emits row-major K hi/lo.  Scratch reused.
    conv_split_kernel<<<convGrid, blk, 0, stream>>>(key, AspH, AspL);
    conv_splitT_kernel<<<tGrid, blk, 0, stream>>>(Wk, WTh, WTl);
    proj_mfma_kernel<<<pGrid, blk, 0, stream>>>(AspH, AspL, WTh, WTl, bk, Khi, Klo, 0);

    // V projection: split-K fp32 (16 splits -> 1024 blocks), then reduce+bias.
    gemm_splitk_kernel<<<dim3(DK / 64, MROWS / 64, 16), blk, 0, stream>>>(
        value, 0, Wv, 0, Pv, MROWS, DK, DMODEL, 16);
    reduce_bias_kernel<<<dim3((int)((long long)MROWS * DK / 1024)), blk, 0, stream>>>(
        Pv, bv, Vb, (long long)MROWS * DK, 16, DK);

    // Softmax denominators (k-split partial sums).  Reciprocal is fused into
    // attn_avg (reads raw sums).
    attn_stats_kernel<<<dim3(SEQ / 256, NHEAD, BATCH * KSPLIT), dim3(512), 0, stream>>>(
        QfH, QfL, Khi, Klo, lBuf);

    // Head-averaged attention matrix.
    attn_avg_kernel<<<dim3(SEQ / 128, SEQ / 128, BATCH), dim3(512), 0, stream>>>(
        QfH, QfL, Khi, Klo, lBuf, avg);

    // attn_output = avg_attn @ V: split-K fp32 (32 splits x 2 batches -> 2048
    // blocks) into dead Qf/K region, then reduce (no bias).
    gemm_splitk_kernel<<<dim3(DK / 64, SEQ / 64, BATCH * 32), blk, 0, stream>>>(
        avg, (long long)SEQ * SEQ, Vb, (long long)SEQ * DK, Pav, SEQ, DK, SEQ, 32);
    reduce_bias_kernel<<<dim3((int)((long long)MROWS * DK / 1024)), blk, 0, stream>>>(
        Pav, nullptr, ao, (long long)MROWS * DK, 32, DK);

    // output = attn_output @ Wo + bo
    gemm_bias_kernel<<<dim3(DMODEL / 64, MROWS / 64, 1), blk, 0, stream>>>(
        ao, 0, Wo, 0, bo, out, 0, MROWS, DMODEL, DK);
}

// Round 10
// 356.236 us; speedup vs baseline: 1.1541x; 1.0039x over previous
//
#include <hip/hip_runtime.h>

// Problem constants
#define BATCH 2
#define SEQ   2048
#define DMODEL 1024
#define NHEAD 16
#define DK    64
#define MROWS (BATCH * SEQ)   // 4096
#define KSPLIT 4

using bf16x8 = __attribute__((ext_vector_type(8))) short;  // 8 bf16 (4 VGPRs)
using f32x4  = __attribute__((ext_vector_type(4))) float;  // MFMA C/D

__device__ __forceinline__ unsigned short f2bf_rne(float x) {
    unsigned u = __float_as_uint(x);
    u += 0x7FFFu + ((u >> 16) & 1u);
    return (unsigned short)(u >> 16);
}
__device__ __forceinline__ float bf2f(unsigned short h) {
    return __uint_as_float((unsigned)h << 16);
}

// Fragment-major layout for the MFMA A operand (Q), indexed by GLOBAL row.
__device__ __forceinline__ long long qf_addr(int row, int d) {
    const int qt = row >> 4, lid = row & 15;
    const int hh = d >> 6, ch = (d >> 3) & 7, j = d & 7;
    return ((((long long)qt * NHEAD + hh) * 8 + ch) * 16 + lid) * 8 + j;
}

// ---------------------------------------------------------------------------
// Elementwise split fp32 -> (hi, lo) bf16.  n must be /1024.
// ---------------------------------------------------------------------------
__global__ __launch_bounds__(256) void conv_split_kernel(
    const float* __restrict__ x, unsigned short* __restrict__ hi,
    unsigned short* __restrict__ lo)
{
    const long long i = ((long long)blockIdx.x * 256 + threadIdx.x) * 4;
    float4 v = *(const float4*)&x[i];
    ushort4 h4, l4;
    unsigned short h;
    h = f2bf_rne(v.x); h4.x = h; l4.x = f2bf_rne(v.x - bf2f(h));
    h = f2bf_rne(v.y); h4.y = h; l4.y = f2bf_rne(v.y - bf2f(h));
    h = f2bf_rne(v.z); h4.z = h; l4.z = f2bf_rne(v.z - bf2f(h));
    h = f2bf_rne(v.w); h4.w = h; l4.w = f2bf_rne(v.w - bf2f(h));
    *(ushort4*)&hi[i] = h4;
    *(ushort4*)&lo[i] = l4;
}

// ---------------------------------------------------------------------------
// Transpose + split: W[K=1024][N=1024] fp32 -> WT hi/lo [N][K] bf16.
// 64x64 tile per block via LDS.
// ---------------------------------------------------------------------------
__global__ __launch_bounds__(256) void conv_splitT_kernel(
    const float* __restrict__ W, unsigned short* __restrict__ hiT,
    unsigned short* __restrict__ loT)
{
    const int k0 = blockIdx.y * 64;
    const int n0 = blockIdx.x * 64;
    const int tid = threadIdx.x;
    __shared__ float T[64][68];
#pragma unroll
    for (int it = 0; it < 4; ++it) {
        const int r = it * 16 + (tid >> 4);
        const int c = (tid & 15) * 4;
        float4 v = *(const float4*)&W[(long long)(k0 + r) * DMODEL + n0 + c];
        T[r][c] = v.x; T[r][c + 1] = v.y; T[r][c + 2] = v.z; T[r][c + 3] = v.w;
    }
    __syncthreads();
#pragma unroll
    for (int it = 0; it < 4; ++it) {
        const int n = it * 16 + (tid >> 4);
        const int kc = (tid & 15) * 4;
        ushort4 h4, l4;
        float v; unsigned short h;
        v = T[kc + 0][n]; h = f2bf_rne(v); h4.x = h; l4.x = f2bf_rne(v - bf2f(h));
        v = T[kc + 1][n]; h = f2bf_rne(v); h4.y = h; l4.y = f2bf_rne(v - bf2f(h));
        v = T[kc + 2][n]; h = f2bf_rne(v); h4.z = h; l4.z = f2bf_rne(v - bf2f(h));
        v = T[kc + 3][n]; h = f2bf_rne(v); h4.w = h; l4.w = f2bf_rne(v - bf2f(h));
        const long long off = (long long)(n0 + n) * DMODEL + k0 + kc;
        *(ushort4*)&hiT[off] = h4;
        *(ushort4*)&loT[off] = l4;
    }
}

// ---------------------------------------------------------------------------
// Split-bf16 MFMA projection GEMM v2: C = A @ W + bias, M=4096, N=K=1024.
// 64n x 128m tiles -> grid 16x32 = 512 blocks (2/CU).  BK=64.  Staging via
// global_load_lds into linear [rows][64] hi/lo tiles with the 16B-slot XOR
// swizzle (physslot = slot ^ (row&7)).  fp32 accumulation chain order
// identical to v1 -> bit-identical output.
// ---------------------------------------------------------------------------
#define PA_HALF 8192    // ushorts: 128 rows x 64
#define PA_TILE 16384   // 32 KB
#define PB_HALF 4096    // 64 rows x 64
#define PB_TILE 8192    // 16 KB

__global__ __launch_bounds__(256, 2) void proj_mfma_kernel(
    const unsigned short* __restrict__ AH, const unsigned short* __restrict__ AL,
    const unsigned short* __restrict__ BTH, const unsigned short* __restrict__ BTL,
    const float* __restrict__ bias,
    unsigned short* __restrict__ OH, unsigned short* __restrict__ OL, int fragQ)
{
    const int n0 = blockIdx.x * 64;
    const int m0 = blockIdx.y * 128;
    const int tid = threadIdx.x;
    const int w = tid >> 6, lane = tid & 63;
    const int quad = lane >> 4, lid = lane & 15;
    const int rsub = lane >> 3;            // row within 8-row chunk
    const int slot = (lane & 7) ^ rsub;    // logical 16B slot this lane fetches

    __shared__ unsigned short As[PA_TILE];   // 32 KB (hi ++ lo)
    __shared__ unsigned short Bs[PB_TILE];   // 16 KB (hi ++ lo)

    f32x4 acc[2][4] = {};   // wave w owns m rows w*32..w*32+31; all 64 n cols

    for (int kc = 0; kc < DMODEL; kc += 64) {
        __syncthreads();                   // previous compute done, LDS free
        // Stage A-tile: 32 chunks (16 hi + 16 lo) of 8 rows x 128 B.
#pragma unroll
        for (int it = 0; it < 8; ++it) {
            const int c = it * 4 + w;
            const int half = c >> 4;
            const int row  = (c & 15) * 8 + rsub;
            const unsigned short* src = half ? AL : AH;
            const unsigned short* g = &src[(long long)(m0 + row) * DMODEL + kc + slot * 8];
            __builtin_amdgcn_global_load_lds(
                (const __attribute__((address_space(1))) unsigned int*)g,
                (__attribute__((address_space(3))) unsigned int*)(As + c * 512),
                16, 0, 0);
        }
        // Stage B-tile: 16 chunks (8 hi + 8 lo).
#pragma unroll
        for (int it = 0; it < 4; ++it) {
            const int c = it * 4 + w;
            const int half = c >> 3;
            const int row  = (c & 7) * 8 + rsub;
            const unsigned short* src = half ? BTL : BTH;
            const unsigned short* g = &src[(long long)(n0 + row) * DMODEL + kc + slot * 8];
            __builtin_amdgcn_global_load_lds(
                (const __attribute__((address_space(1))) unsigned int*)g,
                (__attribute__((address_space(3))) unsigned int*)(Bs + c * 512),
                16, 0, 0);
        }
        __syncthreads();                   // drains loads; tile ready

#pragma unroll
        for (int ks = 0; ks < 2; ++ks) {   // two 32-k sub-chunks, in k order
            bf16x8 ah[2], al_[2], bh[4], bl[4];
#pragma unroll
            for (int mt = 0; mt < 2; ++mt) {
                const int r = w * 32 + mt * 16 + lid;
                const int o = r * 64 + (((quad + 4 * ks) ^ (r & 7)) * 8);
                ah[mt]  = *(const bf16x8*)&As[o];
                al_[mt] = *(const bf16x8*)&As[PA_HALF + o];
            }
#pragma unroll
            for (int nt = 0; nt < 4; ++nt) {
                const int rn = nt * 16 + lid;
                const int o = rn * 64 + (((quad + 4 * ks) ^ (rn & 7)) * 8);
                bh[nt] = *(const bf16x8*)&Bs[o];
                bl[nt] = *(const bf16x8*)&Bs[PB_HALF + o];
            }
#pragma unroll
            for (int mt = 0; mt < 2; ++mt)
#pragma unroll
                for (int nt = 0; nt < 4; ++nt) {
                    acc[mt][nt] = __builtin_amdgcn_mfma_f32_16x16x32_bf16(ah[mt],  bh[nt], acc[mt][nt], 0, 0, 0);
                    acc[mt][nt] = __builtin_amdgcn_mfma_f32_16x16x32_bf16(ah[mt],  bl[nt], acc[mt][nt], 0, 0, 0);
                    acc[mt][nt] = __builtin_amdgcn_mfma_f32_16x16x32_bf16(al_[mt], bh[nt], acc[mt][nt], 0, 0, 0);
                }
        }
    }

    float bv[4];
#pragma unroll
    for (int nt = 0; nt < 4; ++nt)
        bv[nt] = bias[n0 + nt * 16 + lid];

#pragma unroll
    for (int mt = 0; mt < 2; ++mt)
#pragma unroll
        for (int nt = 0; nt < 4; ++nt) {
            const int col = n0 + nt * 16 + lid;
#pragma unroll
            for (int r = 0; r < 4; ++r) {
                const int row = m0 + w * 32 + mt * 16 + quad * 4 + r;
                const float val = acc[mt][nt][r] + bv[nt];
                const unsigned short h = f2bf_rne(val);
                const unsigned short l = f2bf_rne(val - bf2f(h));
                if (fragQ) {
                    const long long fa = qf_addr(row, col);
                    OH[fa] = h; OL[fa] = l;
                } else {
                    const long long off = (long long)row * DMODEL + col;
                    OH[off] = h; OL[off] = l;
                }
            }
        }
}

// ---------------------------------------------------------------------------
// fp32 tiled GEMM (still used for out proj).
// ---------------------------------------------------------------------------
__global__ __launch_bounds__(256) void gemm_bias_kernel(
    const float* __restrict__ A, long long sA,
    const float* __restrict__ W, long long sW,
    const float* __restrict__ bias,
    float* __restrict__ C, long long sC,
    int M, int N, int K)
{
    A += (long long)blockIdx.z * sA;
    W += (long long)blockIdx.z * sW;
    C += (long long)blockIdx.z * sC;
    const int n0 = blockIdx.x * 64;
    const int m0 = blockIdx.y * 64;

    __shared__ float As[16][68];
    __shared__ float Bs[16][68];

    const int tid = threadIdx.x;
    const int tm = (tid >> 4) << 2;
    const int tn = (tid & 15) << 2;
    const int arow = tid >> 2, ak = (tid & 3) << 2;
    const int brow = tid >> 4, bn = (tid & 15) << 2;

    float acc[4][4] = {};

    for (int k0 = 0; k0 < K; k0 += 16) {
        float4 av = *(const float4*)&A[(long long)(m0 + arow) * K + k0 + ak];
        float4 wv = *(const float4*)&W[(long long)(k0 + brow) * N + n0 + bn];
        As[ak + 0][arow] = av.x;
        As[ak + 1][arow] = av.y;
        As[ak + 2][arow] = av.z;
        As[ak + 3][arow] = av.w;
        *(float4*)&Bs[brow][bn] = wv;
        __syncthreads();
#pragma unroll
        for (int kk = 0; kk < 16; ++kk) {
            float4 a4 = *(const float4*)&As[kk][tm];
            float4 b4 = *(const float4*)&Bs[kk][tn];
            float aa[4] = {a4.x, a4.y, a4.z, a4.w};
            float bb[4] = {b4.x, b4.y, b4.z, b4.w};
#pragma unroll
            for (int i = 0; i < 4; ++i)
#pragma unroll
                for (int j = 0; j < 4; ++j)
                    acc[i][j] = fmaf(aa[i], bb[j], acc[i][j]);
        }
        __syncthreads();
    }

    float4 bv = make_float4(0.f, 0.f, 0.f, 0.f);
    if (bias) bv = *(const float4*)&bias[n0 + tn];
#pragma unroll
    for (int i = 0; i < 4; ++i) {
        float4 o = make_float4(acc[i][0] + bv.x, acc[i][1] + bv.y,
                               acc[i][2] + bv.z, acc[i][3] + bv.w);
        *(float4*)&C[(long long)(m0 + tm + i) * N + n0 + tn] = o;
    }
}

// ---------------------------------------------------------------------------
// Split-K fp32 GEMM: partials P[s][b*M+m][n] = A_b[m, kb:kb+kl] @ W_b[kb:kb+kl, n]
// ---------------------------------------------------------------------------
__global__ __launch_bounds__(256) void gemm_splitk_kernel(
    const float* __restrict__ A, long long sA,
    const float* __restrict__ W, long long sW,
    float* __restrict__ P,
    int M, int N, int K, int nsplit)
{
    const int nbatch = gridDim.z / nsplit;
    const int b = blockIdx.z / nsplit;
    const int s = blockIdx.z % nsplit;
    A += (long long)b * sA;
    W += (long long)b * sW;
    float* Pout = P + ((long long)s * nbatch + b) * M * N;

    const int n0 = blockIdx.x * 64;
    const int m0 = blockIdx.y * 64;
    const int kb = s * (K / nsplit);
    const int kl = K / nsplit;

    __shared__ float As[16][68];
    __shared__ float Bs[16][68];

    const int tid = threadIdx.x;
    const int tm = (tid >> 4) << 2;
    const int tn = (tid & 15) << 2;
    const int arow = tid >> 2, ak = (tid & 3) << 2;
    const int brow = tid >> 4, bn = (tid & 15) << 2;

    float acc[4][4] = {};

    for (int k0 = 0; k0 < kl; k0 += 16) {
        float4 av = *(const float4*)&A[(long long)(m0 + arow) * K + kb + k0 + ak];
        float4 wv = *(const float4*)&W[(long long)(kb + k0 + brow) * N + n0 + bn];
        As[ak + 0][arow] = av.x;
        As[ak + 1][arow] = av.y;
        As[ak + 2][arow] = av.z;
        As[ak + 3][arow] = av.w;
        *(float4*)&Bs[brow][bn] = wv;
        __syncthreads();
#pragma unroll
        for (int kk = 0; kk < 16; ++kk) {
            float4 a4 = *(const float4*)&As[kk][tm];
            float4 b4 = *(const float4*)&Bs[kk][tn];
            float aa[4] = {a4.x, a4.y, a4.z, a4.w};
            float bb[4] = {b4.x, b4.y, b4.z, b4.w};
#pragma unroll
            for (int i = 0; i < 4; ++i)
#pragma unroll
                for (int j = 0; j < 4; ++j)
                    acc[i][j] = fmaf(aa[i], bb[j], acc[i][j]);
        }
        __syncthreads();
    }

#pragma unroll
    for (int i = 0; i < 4; ++i) {
        float4 o = make_float4(acc[i][0], acc[i][1], acc[i][2], acc[i][3]);
        *(float4*)&Pout[(long long)(m0 + tm + i) * N + n0 + tn] = o;
    }
}

// C[i] = bias[i % N] + sum_s P[s*stride + i]   (vectorized, bias optional)
__global__ __launch_bounds__(256) void reduce_bias_kernel(
    const float* __restrict__ P, const float* __restrict__ bias,
    float* __restrict__ C, long long stride, int nsplit, int N)
{
    const long long i = ((long long)blockIdx.x * 256 + threadIdx.x) * 4;
    float4 s = *(const float4*)&P[i];
    for (int k = 1; k < nsplit; ++k) {
        float4 v = *(const float4*)&P[(long long)k * stride + i];
        s.x += v.x; s.y += v.y; s.z += v.z; s.w += v.w;
    }
    if (bias) {
        const int n = (int)(i % N);
        float4 b4 = *(const float4*)&bias[n];
        s.x += b4.x; s.y += b4.y; s.z += b4.z; s.w += b4.w;
    }
    *(float4*)&C[i] = s;
}

// ---------------------------------------------------------------------------
// Direct global->LDS staging of one 128-key x 64-d (hi+lo) K tile, 32 KB,
// by an 8-wave (512-thread) block.  Zero VGPRs hold staged data.
// Linear layout + 16B-slot XOR swizzle (physslot = slot ^ (row&7)).
// ---------------------------------------------------------------------------
#define HALF_USH 8192
#define TILE_USH 16384   // 32 KB

__device__ __forceinline__ void stage_issue(
    const unsigned short* __restrict__ Khi, const unsigned short* __restrict__ Klo,
    unsigned short* KsBuf, long long grow0, int h, int w, int lane)
{
    const int rsub = lane >> 3;            // row within 8-row chunk
    const int slot = (lane & 7) ^ rsub;    // logical 16B slot this lane fetches
#pragma unroll
    for (int it = 0; it < 4; ++it) {
        const int c = it * 8 + w;          // chunk 0..31 (wave-uniform), 1 KB each
        const int half = c >> 4;
        const int row  = (c & 15) * 8 + rsub;
        const unsigned short* src = half ? Klo : Khi;
        const unsigned short* g = &src[(grow0 + row) * DMODEL + h * 64 + slot * 8];
        __builtin_amdgcn_global_load_lds(
            (const __attribute__((address_space(1))) unsigned int*)g,
            (__attribute__((address_space(3))) unsigned int*)(KsBuf + c * 512),
            16, 0, 0);
    }
}

__device__ __forceinline__ f32x4 mfma3(bf16x8 ah, bf16x8 al, bf16x8 bh, bf16x8 bl, f32x4 s) {
    s = __builtin_amdgcn_mfma_f32_16x16x32_bf16(ah, bh, s, 0, 0, 0);
    s = __builtin_amdgcn_mfma_f32_16x16x32_bf16(ah, bl, s, 0, 0, 0);
    s = __builtin_amdgcn_mfma_f32_16x16x32_bf16(al, bh, s, 0, 0, 0);
    return s;
}

// ---------------------------------------------------------------------------
// Stats: partial row-sums of exp(QK^T/8) into lsum (atomicAdd, k-split=4).
// 512 threads: 8 waves x 32 q-rows (mt=2) -> Q-tile 256, 128-key K tiles.
// XCD-chunked work swizzle (1024 blocks, %8==0): same-z (b,kbase) work
// co-locates on one XCD so K panels are served from local L2.
// ---------------------------------------------------------------------------
__global__ __launch_bounds__(512, 4) void attn_stats_kernel(
    const unsigned short* __restrict__ QfH, const unsigned short* __restrict__ QfL,
    const unsigned short* __restrict__ Khi, const unsigned short* __restrict__ Klo,
    float* __restrict__ lsum)
{
    int lin = blockIdx.x + 8 * (blockIdx.y + 16 * blockIdx.z);   // 1024 blocks
    lin = (lin & 7) * 128 + (lin >> 3);                          // bijective
    const int q0 = (lin & 7) * 256;
    const int h  = (lin >> 3) & 15;
    const int zz = lin >> 7;
    const int b  = zz >> 2;
    const int kbase = (zz & 3) * (SEQ / KSPLIT);
    const int tid = threadIdx.x;
    const int w = tid >> 6, lane = tid & 63;
    const int quad = lane >> 4, lid = lane & 15;

    __shared__ unsigned short Ks[2 * TILE_USH];   // 64 KB, double buffer

    bf16x8 ah[2][2], al[2][2];
#pragma unroll
    for (int mt = 0; mt < 2; ++mt) {
        const long long qt = (long long)(b * SEQ + q0) / 16 + w * 2 + mt;
#pragma unroll
        for (int ks = 0; ks < 2; ++ks) {
            const long long fa = (((qt * NHEAD + h) * 8 + (quad + 4 * ks)) * 16 + lid) * 8;
            ah[mt][ks] = *(const bf16x8*)&QfH[fa];
            al[mt][ks] = *(const bf16x8*)&QfL[fa];
        }
    }

    float ls[2][4] = {};
    const long long grow0 = (long long)b * SEQ + kbase;

    stage_issue(Khi, Klo, Ks, grow0, h, w, lane);
    __syncthreads();                       // buf0 ready (vmcnt drain)

    for (int kc = 0; kc < SEQ / KSPLIT; kc += 128) {
        const int buf = (kc >> 7) & 1;
        if (kc + 128 < SEQ / KSPLIT)
            stage_issue(Khi, Klo, Ks + (buf ^ 1) * TILE_USH,
                        grow0 + kc + 128, h, w, lane);   // flies under compute
        const unsigned short* Kc = Ks + buf * TILE_USH;

#pragma unroll
        for (int kt = 0; kt < 8; ++kt) {
            const int rr = kt * 16 + lid;
            const int sw = rr & 7;
            bf16x8 bh[2], bl[2];
#pragma unroll
            for (int ks = 0; ks < 2; ++ks) {
                const int o = rr * 64 + (((quad + 4 * ks) ^ sw) * 8);
                bh[ks] = *(const bf16x8*)&Kc[o];
                bl[ks] = *(const bf16x8*)&Kc[HALF_USH + o];
            }
#pragma unroll
            for (int mt = 0; mt < 2; ++mt) {
                f32x4 s = {0.f, 0.f, 0.f, 0.f};
                __builtin_amdgcn_s_setprio(1);
#pragma unroll
                for (int ks = 0; ks < 2; ++ks)
                    s = mfma3(ah[mt][ks], al[mt][ks], bh[ks], bl[ks], s);
                __builtin_amdgcn_s_setprio(0);
#pragma unroll
                for (int r = 0; r < 4; ++r)
                    ls[mt][r] += __expf(s[r] * 0.125f);
            }
        }
        __syncthreads();                   // next buf loaded; cur free to overwrite
    }

#pragma unroll
    for (int off = 1; off < 16; off <<= 1)
#pragma unroll
        for (int mt = 0; mt < 2; ++mt)
#pragma unroll
            for (int r = 0; r < 4; ++r)
                ls[mt][r] += __shfl_xor(ls[mt][r], off);

    if (lid == 0) {
        const long long base = ((long long)(b * NHEAD + h)) * SEQ + q0 + w * 32 + quad * 4;
#pragma unroll
        for (int mt = 0; mt < 2; ++mt)
#pragma unroll
            for (int r = 0; r < 4; ++r)
                atomicAdd(&lsum[base + mt * 16 + r], ls[mt][r]);
    }
}

// lsum -> c = 1/(16*l)   (done once here; avg reads precomputed reciprocals)
__global__ __launch_bounds__(256) void recip_kernel(float* __restrict__ p) {
    const int i = blockIdx.x * 256 + threadIdx.x;
    p[i] = 0.0625f / p[i];
}

// ---------------------------------------------------------------------------
// Avg: block owns 128x128 (q,k) tile; loops 16 heads; 8 waves x 16 q-rows
// (R4 geometry, best measured).  Kept from R9: XCD-chunked work swizzle
// (FETCH 74->54 MB), Q-fragment register double-buffer, setprio.  Reverted
// from R9: recip fusion (it re-did each division 16x -> VALUBusy 39->48;
// reciprocals are precomputed by recip_kernel again).
// ---------------------------------------------------------------------------
__global__ __launch_bounds__(512, 4) void attn_avg_kernel(
    const unsigned short* __restrict__ QfH, const unsigned short* __restrict__ QfL,
    const unsigned short* __restrict__ Khi, const unsigned short* __restrict__ Klo,
    const float* __restrict__ cIn, float* __restrict__ avg)
{
    int lin = blockIdx.x + 16 * (blockIdx.y + 16 * blockIdx.z);  // 512 blocks
    lin = (lin & 7) * 64 + (lin >> 3);                           // bijective
    const int q0 = (lin & 15) * 128;
    const int k0 = ((lin >> 4) & 15) * 128;
    const int b  = lin >> 8;
    const int tid = threadIdx.x;
    const int w = tid >> 6, lane = tid & 63;
    const int quad = lane >> 4, lid = lane & 15;

    __shared__ unsigned short Ks[2 * TILE_USH];   // 64 KB, double buffer

    f32x4 acc[8] = {};
    const long long grow0 = (long long)b * SEQ + k0;
    const long long qt = (long long)(b * SEQ + q0) / 16 + w;
    const long long cb0 = ((long long)b * NHEAD) * SEQ + q0 + w * 16 + quad * 4;

    // Q/recip for head 0 (prologue).
    bf16x8 ahC[2], alC[2];
    float cC[4];
#pragma unroll
    for (int ks = 0; ks < 2; ++ks) {
        const long long fa = (((qt * NHEAD + 0) * 8 + (quad + 4 * ks)) * 16 + lid) * 8;
        ahC[ks] = *(const bf16x8*)&QfH[fa];
        alC[ks] = *(const bf16x8*)&QfL[fa];
    }
#pragma unroll
    for (int r = 0; r < 4; ++r)
        cC[r] = cIn[cb0 + r];

    stage_issue(Khi, Klo, Ks, grow0, 0, w, lane);
    __syncthreads();                       // buf0 ready

    for (int h = 0; h < NHEAD; ++h) {
        const int buf = h & 1;
        if (h + 1 < NHEAD)
            stage_issue(Khi, Klo, Ks + (buf ^ 1) * TILE_USH,
                        grow0, h + 1, w, lane);          // K flies under compute

        // Prefetch Q/recip for head h+1 (flies under compute; consumed after
        // the barrier via the register swap below).
        bf16x8 ahN[2], alN[2];
        float cN[4];
        if (h + 1 < NHEAD) {
#pragma unroll
            for (int ks = 0; ks < 2; ++ks) {
                const long long fa = (((qt * NHEAD + (h + 1)) * 8 + (quad + 4 * ks)) * 16 + lid) * 8;
                ahN[ks] = *(const bf16x8*)&QfH[fa];
                alN[ks] = *(const bf16x8*)&QfL[fa];
            }
#pragma unroll
            for (int r = 0; r < 4; ++r)
                cN[r] = cIn[cb0 + (long long)(h + 1) * SEQ + r];
        }

        const unsigned short* Kc = Ks + buf * TILE_USH;

#pragma unroll
        for (int kt = 0; kt < 8; ++kt) {
            const int rr = kt * 16 + lid;
            const int sw = rr & 7;
            bf16x8 bh[2], bl[2];
#pragma unroll
            for (int ks = 0; ks < 2; ++ks) {
                const int o = rr * 64 + (((quad + 4 * ks) ^ sw) * 8);
                bh[ks] = *(const bf16x8*)&Kc[o];
                bl[ks] = *(const bf16x8*)&Kc[HALF_USH + o];
            }
            f32x4 s = {0.f, 0.f, 0.f, 0.f};
            __builtin_amdgcn_s_setprio(1);
#pragma unroll
            for (int ks = 0; ks < 2; ++ks)
                s = mfma3(ahC[ks], alC[ks], bh[ks], bl[ks], s);
            __builtin_amdgcn_s_setprio(0);
#pragma unroll
            for (int r = 0; r < 4; ++r)
                acc[kt][r] = fmaf(__expf(s[r] * 0.125f), cC[r], acc[kt][r]);
        }
        __syncthreads();                   // next buf loaded; cur free

        // Swap prefetched head state into current (register moves).
        if (h + 1 < NHEAD) {
#pragma unroll
            for (int ks = 0; ks < 2; ++ks) { ahC[ks] = ahN[ks]; alC[ks] = alN[ks]; }
#pragma unroll
            for (int r = 0; r < 4; ++r) cC[r] = cN[r];
        }
    }

#pragma unroll
    for (int kt = 0; kt < 8; ++kt)
#pragma unroll
        for (int r = 0; r < 4; ++r) {
            const int q = q0 + w * 16 + quad * 4 + r;
            avg[((long long)(b * SEQ + q)) * SEQ + k0 + kt * 16 + lid] = acc[kt][r];
        }
}

// ---------------------------------------------------------------------------
extern "C" void kernel_launch(void* const* d_in, const int* in_sizes, int n_in,
                              void* d_out, int out_size, void* d_ws, size_t ws_size,
                              hipStream_t stream)
{
    const float* query = (const float*)d_in[0];
    const float* key   = (const float*)d_in[1];
    const float* value = (const float*)d_in[2];
    const float* Wq    = (const float*)d_in[3];
    const float* bq    = (const float*)d_in[4];
    const float* Wk    = (const float*)d_in[5];
    const float* bk    = (const float*)d_in[6];
    const float* Wv    = (const float*)d_in[7];
    const float* bv    = (const float*)d_in[8];
    const float* Wo    = (const float*)d_in[9];
    const float* bo    = (const float*)d_in[10];

    float* out = (float*)d_out;                         // [B,S,DMODEL]
    float* avg = out + (long long)BATCH * SEQ * DMODEL; // [B,S,S]

    const long long QKN = (long long)MROWS * DMODEL;    // 4.2M elems
    unsigned short* QfH = (unsigned short*)d_ws;        // frag-major, 8 MB each
    unsigned short* QfL = QfH + QKN;
    unsigned short* Khi = QfL + QKN;                    // row-major
    unsigned short* Klo = Khi + QKN;
    unsigned short* AspH = Klo + QKN;                   // split input scratch (reused)
    unsigned short* AspL = AspH + QKN;
    unsigned short* WTh  = AspL + QKN;                  // W^T split, 2 MB each
    unsigned short* WTl  = WTh + (long long)DMODEL * DMODEL;
    float* Vb   = (float*)(WTl + (long long)DMODEL * DMODEL); // 4096x64 fp32
    float* lBuf = Vb + (long long)MROWS * DK;                 // B*H*S
    float* ao   = lBuf + (long long)BATCH * NHEAD * SEQ;      // 4096x64

    // Dead-region reuse for split-K partials (in-stream ordering guarantees):
    //  - V proj partials (16 x 1 MB) live in AspH..AspL (dead after proj_mfma(K)).
    //  - avg@V partials (32 x 1 MB) live in QfH..Klo (dead after attn_avg).
    float* Pv  = (float*)AspH;
    float* Pav = (float*)QfH;

    dim3 blk(256);
    hipMemsetAsync(lBuf, 0, (size_t)BATCH * NHEAD * SEQ * sizeof(float), stream);

    const int convGrid = (int)(QKN / (256 * 4));        // 4096
    dim3 tGrid(DMODEL / 64, DMODEL / 64);               // 16x16
    dim3 pGrid(DMODEL / 64, MROWS / 128);               // 16x32 = 512 blocks

    // Q projection (MFMA split-bf16), emits fragment-major Q hi/lo.
    conv_split_kernel<<<convGrid, blk, 0, stream>>>(query, AspH, AspL);
    conv_splitT_kernel<<<tGrid, blk, 0, stream>>>(Wq, WTh, WTl);
    proj_mfma_kernel<<<pGrid, blk, 0, stream>>>(AspH, AspL, WTh, WTl, bq, QfH, QfL, 1);

    // K projection (MFMA split-bf16), emits row-major K hi/lo.  Scratch reused.
    conv_split_kernel<<<convGrid, blk, 0, stream>>>(key, AspH, AspL);
    conv_splitT_kernel<<<tGrid, blk, 0, stream>>>(Wk, WTh, WTl);
    proj_mfma_kernel<<<pGrid, blk, 0, stream>>>(AspH, AspL, WTh, WTl, bk, Khi, Klo, 0);

    // V projection: split-K fp32 (16 splits -> 1024 blocks), then reduce+bias.
    gemm_splitk_kernel<<<dim3(DK / 64, MROWS / 64, 16), blk, 0, stream>>>(
        value, 0, Wv, 0, Pv, MROWS, DK, DMODEL, 16);
    reduce_bias_kernel<<<dim3((int)((long long)MROWS * DK / 1024)), blk, 0, stream>>>(
        Pv, bv, Vb, (long long)MROWS * DK, 16, DK);

    // Softmax denominators (k-split partial sums), then reciprocal (once).
    attn_stats_kernel<<<dim3(SEQ / 256, NHEAD, BATCH * KSPLIT), dim3(512), 0, stream>>>(
        QfH, QfL, Khi, Klo, lBuf);
    recip_kernel<<<dim3(BATCH * NHEAD * SEQ / 256), blk, 0, stream>>>(lBuf);

    // Head-averaged attention matrix.
    attn_avg_kernel<<<dim3(SEQ / 128, SEQ / 128, BATCH), dim3(512), 0, stream>>>(
        QfH, QfL, Khi, Klo, lBuf, avg);

    // attn_output = avg_attn @ V: split-K fp32 (32 splits x 2 batches -> 2048
    // blocks) into dead Qf/K region, then reduce (no bias).
    gemm_splitk_kernel<<<dim3(DK / 64, SEQ / 64, BATCH * 32), blk, 0, stream>>>(
        avg, (long long)SEQ * SEQ, Vb, (long long)SEQ * DK, Pav, SEQ, DK, SEQ, 32);
    reduce_bias_kernel<<<dim3((int)((long long)MROWS * DK / 1024)), blk, 0, stream>>>(
        Pav, nullptr, ao, (long long)MROWS * DK, 32, DK);

    // output = attn_output @ Wo + bo
    gemm_bias_kernel<<<dim3(DMODEL / 64, MROWS / 64, 1), blk, 0, stream>>>(
        ao, 0, Wo, 0, bo, out, 0, MROWS, DMODEL, DK);
}

// Round 11
// 352.447 us; speedup vs baseline: 1.1665x; 1.0108x over previous
//
#include <hip/hip_runtime.h>

// Problem constants
#define BATCH 2
#define SEQ   2048
#define DMODEL 1024
#define NHEAD 16
#define DK    64
#define MROWS (BATCH * SEQ)   // 4096
#define KSPLIT 4

using bf16x8 = __attribute__((ext_vector_type(8))) short;  // 8 bf16 (4 VGPRs)
using f32x4  = __attribute__((ext_vector_type(4))) float;  // MFMA C/D

__device__ __forceinline__ unsigned short f2bf_rne(float x) {
    unsigned u = __float_as_uint(x);
    u += 0x7FFFu + ((u >> 16) & 1u);
    return (unsigned short)(u >> 16);
}
__device__ __forceinline__ float bf2f(unsigned short h) {
    return __uint_as_float((unsigned)h << 16);
}

// Fragment-major layout for the MFMA A operand (Q), indexed by GLOBAL row.
__device__ __forceinline__ long long qf_addr(int row, int d) {
    const int qt = row >> 4, lid = row & 15;
    const int hh = d >> 6, ch = (d >> 3) & 7, j = d & 7;
    return ((((long long)qt * NHEAD + hh) * 8 + ch) * 16 + lid) * 8 + j;
}

// ---------------------------------------------------------------------------
// Elementwise split fp32 -> (hi, lo) bf16.  n must be /1024.
// ---------------------------------------------------------------------------
__global__ __launch_bounds__(256) void conv_split_kernel(
    const float* __restrict__ x, unsigned short* __restrict__ hi,
    unsigned short* __restrict__ lo)
{
    const long long i = ((long long)blockIdx.x * 256 + threadIdx.x) * 4;
    float4 v = *(const float4*)&x[i];
    ushort4 h4, l4;
    unsigned short h;
    h = f2bf_rne(v.x); h4.x = h; l4.x = f2bf_rne(v.x - bf2f(h));
    h = f2bf_rne(v.y); h4.y = h; l4.y = f2bf_rne(v.y - bf2f(h));
    h = f2bf_rne(v.z); h4.z = h; l4.z = f2bf_rne(v.z - bf2f(h));
    h = f2bf_rne(v.w); h4.w = h; l4.w = f2bf_rne(v.w - bf2f(h));
    *(ushort4*)&hi[i] = h4;
    *(ushort4*)&lo[i] = l4;
}

// ---------------------------------------------------------------------------
// Transpose + split: W[K=1024][N=1024] fp32 -> WT hi/lo [N][K] bf16.
// 64x64 tile per block via LDS.
// ---------------------------------------------------------------------------
__global__ __launch_bounds__(256) void conv_splitT_kernel(
    const float* __restrict__ W, unsigned short* __restrict__ hiT,
    unsigned short* __restrict__ loT)
{
    const int k0 = blockIdx.y * 64;
    const int n0 = blockIdx.x * 64;
    const int tid = threadIdx.x;
    __shared__ float T[64][68];
#pragma unroll
    for (int it = 0; it < 4; ++it) {
        const int r = it * 16 + (tid >> 4);
        const int c = (tid & 15) * 4;
        float4 v = *(const float4*)&W[(long long)(k0 + r) * DMODEL + n0 + c];
        T[r][c] = v.x; T[r][c + 1] = v.y; T[r][c + 2] = v.z; T[r][c + 3] = v.w;
    }
    __syncthreads();
#pragma unroll
    for (int it = 0; it < 4; ++it) {
        const int n = it * 16 + (tid >> 4);
        const int kc = (tid & 15) * 4;
        ushort4 h4, l4;
        float v; unsigned short h;
        v = T[kc + 0][n]; h = f2bf_rne(v); h4.x = h; l4.x = f2bf_rne(v - bf2f(h));
        v = T[kc + 1][n]; h = f2bf_rne(v); h4.y = h; l4.y = f2bf_rne(v - bf2f(h));
        v = T[kc + 2][n]; h = f2bf_rne(v); h4.z = h; l4.z = f2bf_rne(v - bf2f(h));
        v = T[kc + 3][n]; h = f2bf_rne(v); h4.w = h; l4.w = f2bf_rne(v - bf2f(h));
        const long long off = (long long)(n0 + n) * DMODEL + k0 + kc;
        *(ushort4*)&hiT[off] = h4;
        *(ushort4*)&loT[off] = l4;
    }
}

// ---------------------------------------------------------------------------
// Split-bf16 MFMA projection GEMM v2: C = (A @ W + bias) * oscale.
// M=4096, N=K=1024.  64n x 128m tiles -> 512 blocks (2/CU), BK=64,
// global_load_lds staging with 16B-slot XOR swizzle.
// oscale=0.125 for Q (folds the softmax 1/8 into Q -- power-of-2 scale is
// bit-exact through the bf16 hi/lo split and the MFMA fp32 accumulation,
// so downstream exp() arguments are bit-identical); oscale=1 for K.
// ---------------------------------------------------------------------------
#define PA_HALF 8192    // ushorts: 128 rows x 64
#define PA_TILE 16384   // 32 KB
#define PB_HALF 4096    // 64 rows x 64
#define PB_TILE 8192    // 16 KB

__global__ __launch_bounds__(256, 2) void proj_mfma_kernel(
    const unsigned short* __restrict__ AH, const unsigned short* __restrict__ AL,
    const unsigned short* __restrict__ BTH, const unsigned short* __restrict__ BTL,
    const float* __restrict__ bias,
    unsigned short* __restrict__ OH, unsigned short* __restrict__ OL,
    int fragQ, float oscale)
{
    const int n0 = blockIdx.x * 64;
    const int m0 = blockIdx.y * 128;
    const int tid = threadIdx.x;
    const int w = tid >> 6, lane = tid & 63;
    const int quad = lane >> 4, lid = lane & 15;
    const int rsub = lane >> 3;            // row within 8-row chunk
    const int slot = (lane & 7) ^ rsub;    // logical 16B slot this lane fetches

    __shared__ unsigned short As[PA_TILE];   // 32 KB (hi ++ lo)
    __shared__ unsigned short Bs[PB_TILE];   // 16 KB (hi ++ lo)

    f32x4 acc[2][4] = {};   // wave w owns m rows w*32..w*32+31; all 64 n cols

    for (int kc = 0; kc < DMODEL; kc += 64) {
        __syncthreads();                   // previous compute done, LDS free
        // Stage A-tile: 32 chunks (16 hi + 16 lo) of 8 rows x 128 B.
#pragma unroll
        for (int it = 0; it < 8; ++it) {
            const int c = it * 4 + w;
            const int half = c >> 4;
            const int row  = (c & 15) * 8 + rsub;
            const unsigned short* src = half ? AL : AH;
            const unsigned short* g = &src[(long long)(m0 + row) * DMODEL + kc + slot * 8];
            __builtin_amdgcn_global_load_lds(
                (const __attribute__((address_space(1))) unsigned int*)g,
                (__attribute__((address_space(3))) unsigned int*)(As + c * 512),
                16, 0, 0);
        }
        // Stage B-tile: 16 chunks (8 hi + 8 lo).
#pragma unroll
        for (int it = 0; it < 4; ++it) {
            const int c = it * 4 + w;
            const int half = c >> 3;
            const int row  = (c & 7) * 8 + rsub;
            const unsigned short* src = half ? BTL : BTH;
            const unsigned short* g = &src[(long long)(n0 + row) * DMODEL + kc + slot * 8];
            __builtin_amdgcn_global_load_lds(
                (const __attribute__((address_space(1))) unsigned int*)g,
                (__attribute__((address_space(3))) unsigned int*)(Bs + c * 512),
                16, 0, 0);
        }
        __syncthreads();                   // drains loads; tile ready

#pragma unroll
        for (int ks = 0; ks < 2; ++ks) {   // two 32-k sub-chunks, in k order
            bf16x8 ah[2], al_[2], bh[4], bl[4];
#pragma unroll
            for (int mt = 0; mt < 2; ++mt) {
                const int r = w * 32 + mt * 16 + lid;
                const int o = r * 64 + (((quad + 4 * ks) ^ (r & 7)) * 8);
                ah[mt]  = *(const bf16x8*)&As[o];
                al_[mt] = *(const bf16x8*)&As[PA_HALF + o];
            }
#pragma unroll
            for (int nt = 0; nt < 4; ++nt) {
                const int rn = nt * 16 + lid;
                const int o = rn * 64 + (((quad + 4 * ks) ^ (rn & 7)) * 8);
                bh[nt] = *(const bf16x8*)&Bs[o];
                bl[nt] = *(const bf16x8*)&Bs[PB_HALF + o];
            }
#pragma unroll
            for (int mt = 0; mt < 2; ++mt)
#pragma unroll
                for (int nt = 0; nt < 4; ++nt) {
                    acc[mt][nt] = __builtin_amdgcn_mfma_f32_16x16x32_bf16(ah[mt],  bh[nt], acc[mt][nt], 0, 0, 0);
                    acc[mt][nt] = __builtin_amdgcn_mfma_f32_16x16x32_bf16(ah[mt],  bl[nt], acc[mt][nt], 0, 0, 0);
                    acc[mt][nt] = __builtin_amdgcn_mfma_f32_16x16x32_bf16(al_[mt], bh[nt], acc[mt][nt], 0, 0, 0);
                }
        }
    }

    float bv[4];
#pragma unroll
    for (int nt = 0; nt < 4; ++nt)
        bv[nt] = bias[n0 + nt * 16 + lid];

#pragma unroll
    for (int mt = 0; mt < 2; ++mt)
#pragma unroll
        for (int nt = 0; nt < 4; ++nt) {
            const int col = n0 + nt * 16 + lid;
#pragma unroll
            for (int r = 0; r < 4; ++r) {
                const int row = m0 + w * 32 + mt * 16 + quad * 4 + r;
                const float val = (acc[mt][nt][r] + bv[nt]) * oscale;
                const unsigned short h = f2bf_rne(val);
                const unsigned short l = f2bf_rne(val - bf2f(h));
                if (fragQ) {
                    const long long fa = qf_addr(row, col);
                    OH[fa] = h; OL[fa] = l;
                } else {
                    const long long off = (long long)row * DMODEL + col;
                    OH[off] = h; OL[off] = l;
                }
            }
        }
}

// ---------------------------------------------------------------------------
// fp32 tiled GEMM (still used for out proj).
// ---------------------------------------------------------------------------
__global__ __launch_bounds__(256) void gemm_bias_kernel(
    const float* __restrict__ A, long long sA,
    const float* __restrict__ W, long long sW,
    const float* __restrict__ bias,
    float* __restrict__ C, long long sC,
    int M, int N, int K)
{
    A += (long long)blockIdx.z * sA;
    W += (long long)blockIdx.z * sW;
    C += (long long)blockIdx.z * sC;
    const int n0 = blockIdx.x * 64;
    const int m0 = blockIdx.y * 64;

    __shared__ float As[16][68];
    __shared__ float Bs[16][68];

    const int tid = threadIdx.x;
    const int tm = (tid >> 4) << 2;
    const int tn = (tid & 15) << 2;
    const int arow = tid >> 2, ak = (tid & 3) << 2;
    const int brow = tid >> 4, bn = (tid & 15) << 2;

    float acc[4][4] = {};

    for (int k0 = 0; k0 < K; k0 += 16) {
        float4 av = *(const float4*)&A[(long long)(m0 + arow) * K + k0 + ak];
        float4 wv = *(const float4*)&W[(long long)(k0 + brow) * N + n0 + bn];
        As[ak + 0][arow] = av.x;
        As[ak + 1][arow] = av.y;
        As[ak + 2][arow] = av.z;
        As[ak + 3][arow] = av.w;
        *(float4*)&Bs[brow][bn] = wv;
        __syncthreads();
#pragma unroll
        for (int kk = 0; kk < 16; ++kk) {
            float4 a4 = *(const float4*)&As[kk][tm];
            float4 b4 = *(const float4*)&Bs[kk][tn];
            float aa[4] = {a4.x, a4.y, a4.z, a4.w};
            float bb[4] = {b4.x, b4.y, b4.z, b4.w};
#pragma unroll
            for (int i = 0; i < 4; ++i)
#pragma unroll
                for (int j = 0; j < 4; ++j)
                    acc[i][j] = fmaf(aa[i], bb[j], acc[i][j]);
        }
        __syncthreads();
    }

    float4 bv = make_float4(0.f, 0.f, 0.f, 0.f);
    if (bias) bv = *(const float4*)&bias[n0 + tn];
#pragma unroll
    for (int i = 0; i < 4; ++i) {
        float4 o = make_float4(acc[i][0] + bv.x, acc[i][1] + bv.y,
                               acc[i][2] + bv.z, acc[i][3] + bv.w);
        *(float4*)&C[(long long)(m0 + tm + i) * N + n0 + tn] = o;
    }
}

// ---------------------------------------------------------------------------
// Split-K fp32 GEMM: partials P[s][b*M+m][n] = A_b[m, kb:kb+kl] @ W_b[kb:kb+kl, n]
// ---------------------------------------------------------------------------
__global__ __launch_bounds__(256) void gemm_splitk_kernel(
    const float* __restrict__ A, long long sA,
    const float* __restrict__ W, long long sW,
    float* __restrict__ P,
    int M, int N, int K, int nsplit)
{
    const int nbatch = gridDim.z / nsplit;
    const int b = blockIdx.z / nsplit;
    const int s = blockIdx.z % nsplit;
    A += (long long)b * sA;
    W += (long long)b * sW;
    float* Pout = P + ((long long)s * nbatch + b) * M * N;

    const int n0 = blockIdx.x * 64;
    const int m0 = blockIdx.y * 64;
    const int kb = s * (K / nsplit);
    const int kl = K / nsplit;

    __shared__ float As[16][68];
    __shared__ float Bs[16][68];

    const int tid = threadIdx.x;
    const int tm = (tid >> 4) << 2;
    const int tn = (tid & 15) << 2;
    const int arow = tid >> 2, ak = (tid & 3) << 2;
    const int brow = tid >> 4, bn = (tid & 15) << 2;

    float acc[4][4] = {};

    for (int k0 = 0; k0 < kl; k0 += 16) {
        float4 av = *(const float4*)&A[(long long)(m0 + arow) * K + kb + k0 + ak];
        float4 wv = *(const float4*)&W[(long long)(kb + k0 + brow) * N + n0 + bn];
        As[ak + 0][arow] = av.x;
        As[ak + 1][arow] = av.y;
        As[ak + 2][arow] = av.z;
        As[ak + 3][arow] = av.w;
        *(float4*)&Bs[brow][bn] = wv;
        __syncthreads();
#pragma unroll
        for (int kk = 0; kk < 16; ++kk) {
            float4 a4 = *(const float4*)&As[kk][tm];
            float4 b4 = *(const float4*)&Bs[kk][tn];
            float aa[4] = {a4.x, a4.y, a4.z, a4.w};
            float bb[4] = {b4.x, b4.y, b4.z, b4.w};
#pragma unroll
            for (int i = 0; i < 4; ++i)
#pragma unroll
                for (int j = 0; j < 4; ++j)
                    acc[i][j] = fmaf(aa[i], bb[j], acc[i][j]);
        }
        __syncthreads();
    }

#pragma unroll
    for (int i = 0; i < 4; ++i) {
        float4 o = make_float4(acc[i][0], acc[i][1], acc[i][2], acc[i][3]);
        *(float4*)&Pout[(long long)(m0 + tm + i) * N + n0 + tn] = o;
    }
}

// C[i] = bias[i % N] + sum_s P[s*stride + i]   (vectorized, bias optional)
__global__ __launch_bounds__(256) void reduce_bias_kernel(
    const float* __restrict__ P, const float* __restrict__ bias,
    float* __restrict__ C, long long stride, int nsplit, int N)
{
    const long long i = ((long long)blockIdx.x * 256 + threadIdx.x) * 4;
    float4 s = *(const float4*)&P[i];
    for (int k = 1; k < nsplit; ++k) {
        float4 v = *(const float4*)&P[(long long)k * stride + i];
        s.x += v.x; s.y += v.y; s.z += v.z; s.w += v.w;
    }
    if (bias) {
        const int n = (int)(i % N);
        float4 b4 = *(const float4*)&bias[n];
        s.x += b4.x; s.y += b4.y; s.z += b4.z; s.w += b4.w;
    }
    *(float4*)&C[i] = s;
}

// ---------------------------------------------------------------------------
// Direct global->LDS staging of one 128-key x 64-d (hi+lo) K tile, 32 KB,
// by an 8-wave (512-thread) block.  Zero VGPRs hold staged data.
// Linear layout + 16B-slot XOR swizzle (physslot = slot ^ (row&7)).
// ---------------------------------------------------------------------------
#define HALF_USH 8192
#define TILE_USH 16384   // 32 KB

__device__ __forceinline__ void stage_issue(
    const unsigned short* __restrict__ Khi, const unsigned short* __restrict__ Klo,
    unsigned short* KsBuf, long long grow0, int h, int w, int lane)
{
    const int rsub = lane >> 3;            // row within 8-row chunk
    const int slot = (lane & 7) ^ rsub;    // logical 16B slot this lane fetches
#pragma unroll
    for (int it = 0; it < 4; ++it) {
        const int c = it * 8 + w;          // chunk 0..31 (wave-uniform), 1 KB each
        const int half = c >> 4;
        const int row  = (c & 15) * 8 + rsub;
        const unsigned short* src = half ? Klo : Khi;
        const unsigned short* g = &src[(grow0 + row) * DMODEL + h * 64 + slot * 8];
        __builtin_amdgcn_global_load_lds(
            (const __attribute__((address_space(1))) unsigned int*)g,
            (__attribute__((address_space(3))) unsigned int*)(KsBuf + c * 512),
            16, 0, 0);
    }
}

__device__ __forceinline__ f32x4 mfma3(bf16x8 ah, bf16x8 al, bf16x8 bh, bf16x8 bl, f32x4 s) {
    s = __builtin_amdgcn_mfma_f32_16x16x32_bf16(ah, bh, s, 0, 0, 0);
    s = __builtin_amdgcn_mfma_f32_16x16x32_bf16(ah, bl, s, 0, 0, 0);
    s = __builtin_amdgcn_mfma_f32_16x16x32_bf16(al, bh, s, 0, 0, 0);
    return s;
}

// ---------------------------------------------------------------------------
// Stats: partial row-sums of exp(QK^T/8) into lsum (atomicAdd, k-split=4).
// Q is pre-scaled by 1/8 at projection -> exp argument needs no multiply.
// 512 threads: 8 waves x 32 q-rows (mt=2) -> Q-tile 256, 128-key K tiles.
// XCD-chunked work swizzle (1024 blocks, %8==0).
// ---------------------------------------------------------------------------
__global__ __launch_bounds__(512, 4) void attn_stats_kernel(
    const unsigned short* __restrict__ QfH, const unsigned short* __restrict__ QfL,
    const unsigned short* __restrict__ Khi, const unsigned short* __restrict__ Klo,
    float* __restrict__ lsum)
{
    int lin = blockIdx.x + 8 * (blockIdx.y + 16 * blockIdx.z);   // 1024 blocks
    lin = (lin & 7) * 128 + (lin >> 3);                          // bijective
    const int q0 = (lin & 7) * 256;
    const int h  = (lin >> 3) & 15;
    const int zz = lin >> 7;
    const int b  = zz >> 2;
    const int kbase = (zz & 3) * (SEQ / KSPLIT);
    const int tid = threadIdx.x;
    const int w = tid >> 6, lane = tid & 63;
    const int quad = lane >> 4, lid = lane & 15;

    __shared__ unsigned short Ks[2 * TILE_USH];   // 64 KB, double buffer

    bf16x8 ah[2][2], al[2][2];
#pragma unroll
    for (int mt = 0; mt < 2; ++mt) {
        const long long qt = (long long)(b * SEQ + q0) / 16 + w * 2 + mt;
#pragma unroll
        for (int ks = 0; ks < 2; ++ks) {
            const long long fa = (((qt * NHEAD + h) * 8 + (quad + 4 * ks)) * 16 + lid) * 8;
            ah[mt][ks] = *(const bf16x8*)&QfH[fa];
            al[mt][ks] = *(const bf16x8*)&QfL[fa];
        }
    }

    float ls[2][4] = {};
    const long long grow0 = (long long)b * SEQ + kbase;

    stage_issue(Khi, Klo, Ks, grow0, h, w, lane);
    __syncthreads();                       // buf0 ready (vmcnt drain)

    for (int kc = 0; kc < SEQ / KSPLIT; kc += 128) {
        const int buf = (kc >> 7) & 1;
        if (kc + 128 < SEQ / KSPLIT)
            stage_issue(Khi, Klo, Ks + (buf ^ 1) * TILE_USH,
                        grow0 + kc + 128, h, w, lane);   // flies under compute
        const unsigned short* Kc = Ks + buf * TILE_USH;

#pragma unroll
        for (int kt = 0; kt < 8; ++kt) {
            const int rr = kt * 16 + lid;
            const int sw = rr & 7;
            bf16x8 bh[2], bl[2];
#pragma unroll
            for (int ks = 0; ks < 2; ++ks) {
                const int o = rr * 64 + (((quad + 4 * ks) ^ sw) * 8);
                bh[ks] = *(const bf16x8*)&Kc[o];
                bl[ks] = *(const bf16x8*)&Kc[HALF_USH + o];
            }
#pragma unroll
            for (int mt = 0; mt < 2; ++mt) {
                f32x4 s = {0.f, 0.f, 0.f, 0.f};
                __builtin_amdgcn_s_setprio(1);
#pragma unroll
                for (int ks = 0; ks < 2; ++ks)
                    s = mfma3(ah[mt][ks], al[mt][ks], bh[ks], bl[ks], s);
                __builtin_amdgcn_s_setprio(0);
#pragma unroll
                for (int r = 0; r < 4; ++r)
                    ls[mt][r] += __expf(s[r]);
            }
        }
        __syncthreads();                   // next buf loaded; cur free to overwrite
    }

#pragma unroll
    for (int off = 1; off < 16; off <<= 1)
#pragma unroll
        for (int mt = 0; mt < 2; ++mt)
#pragma unroll
            for (int r = 0; r < 4; ++r)
                ls[mt][r] += __shfl_xor(ls[mt][r], off);

    if (lid == 0) {
        const long long base = ((long long)(b * NHEAD + h)) * SEQ + q0 + w * 32 + quad * 4;
#pragma unroll
        for (int mt = 0; mt < 2; ++mt)
#pragma unroll
            for (int r = 0; r < 4; ++r)
                atomicAdd(&lsum[base + mt * 16 + r], ls[mt][r]);
    }
}

// lsum -> c = 1/(16*l)   (done once here; avg reads precomputed reciprocals)
__global__ __launch_bounds__(256) void recip_kernel(float* __restrict__ p) {
    const int i = blockIdx.x * 256 + threadIdx.x;
    p[i] = 0.0625f / p[i];
}

// ---------------------------------------------------------------------------
// Avg: block owns 128x128 (q,k) tile; loops 16 heads; 8 waves x 16 q-rows
// (R4 geometry).  XCD-chunked work swizzle, Q-fragment register
// double-buffer, setprio, precomputed reciprocals.  Q pre-scaled by 1/8
// at projection -> exp chain is v_exp + v_fma only.
// ---------------------------------------------------------------------------
__global__ __launch_bounds__(512, 4) void attn_avg_kernel(
    const unsigned short* __restrict__ QfH, const unsigned short* __restrict__ QfL,
    const unsigned short* __restrict__ Khi, const unsigned short* __restrict__ Klo,
    const float* __restrict__ cIn, float* __restrict__ avg)
{
    int lin = blockIdx.x + 16 * (blockIdx.y + 16 * blockIdx.z);  // 512 blocks
    lin = (lin & 7) * 64 + (lin >> 3);                           // bijective
    const int q0 = (lin & 15) * 128;
    const int k0 = ((lin >> 4) & 15) * 128;
    const int b  = lin >> 8;
    const int tid = threadIdx.x;
    const int w = tid >> 6, lane = tid & 63;
    const int quad = lane >> 4, lid = lane & 15;

    __shared__ unsigned short Ks[2 * TILE_USH];   // 64 KB, double buffer

    f32x4 acc[8] = {};
    const long long grow0 = (long long)b * SEQ + k0;
    const long long qt = (long long)(b * SEQ + q0) / 16 + w;
    const long long cb0 = ((long long)b * NHEAD) * SEQ + q0 + w * 16 + quad * 4;

    // Q/recip for head 0 (prologue).
    bf16x8 ahC[2], alC[2];
    float cC[4];
#pragma unroll
    for (int ks = 0; ks < 2; ++ks) {
        const long long fa = (((qt * NHEAD + 0) * 8 + (quad + 4 * ks)) * 16 + lid) * 8;
        ahC[ks] = *(const bf16x8*)&QfH[fa];
        alC[ks] = *(const bf16x8*)&QfL[fa];
    }
#pragma unroll
    for (int r = 0; r < 4; ++r)
        cC[r] = cIn[cb0 + r];

    stage_issue(Khi, Klo, Ks, grow0, 0, w, lane);
    __syncthreads();                       // buf0 ready

    for (int h = 0; h < NHEAD; ++h) {
        const int buf = h & 1;
        if (h + 1 < NHEAD)
            stage_issue(Khi, Klo, Ks + (buf ^ 1) * TILE_USH,
                        grow0, h + 1, w, lane);          // K flies under compute

        // Prefetch Q/recip for head h+1 (flies under compute; consumed after
        // the barrier via the register swap below).
        bf16x8 ahN[2], alN[2];
        float cN[4];
        if (h + 1 < NHEAD) {
#pragma unroll
            for (int ks = 0; ks < 2; ++ks) {
                const long long fa = (((qt * NHEAD + (h + 1)) * 8 + (quad + 4 * ks)) * 16 + lid) * 8;
                ahN[ks] = *(const bf16x8*)&QfH[fa];
                alN[ks] = *(const bf16x8*)&QfL[fa];
            }
#pragma unroll
            for (int r = 0; r < 4; ++r)
                cN[r] = cIn[cb0 + (long long)(h + 1) * SEQ + r];
        }

        const unsigned short* Kc = Ks + buf * TILE_USH;

#pragma unroll
        for (int kt = 0; kt < 8; ++kt) {
            const int rr = kt * 16 + lid;
            const int sw = rr & 7;
            bf16x8 bh[2], bl[2];
#pragma unroll
            for (int ks = 0; ks < 2; ++ks) {
                const int o = rr * 64 + (((quad + 4 * ks) ^ sw) * 8);
                bh[ks] = *(const bf16x8*)&Kc[o];
                bl[ks] = *(const bf16x8*)&Kc[HALF_USH + o];
            }
            f32x4 s = {0.f, 0.f, 0.f, 0.f};
            __builtin_amdgcn_s_setprio(1);
#pragma unroll
            for (int ks = 0; ks < 2; ++ks)
                s = mfma3(ahC[ks], alC[ks], bh[ks], bl[ks], s);
            __builtin_amdgcn_s_setprio(0);
#pragma unroll
            for (int r = 0; r < 4; ++r)
                acc[kt][r] = fmaf(__expf(s[r]), cC[r], acc[kt][r]);
        }
        __syncthreads();                   // next buf loaded; cur free

        // Swap prefetched head state into current (register moves).
        if (h + 1 < NHEAD) {
#pragma unroll
            for (int ks = 0; ks < 2; ++ks) { ahC[ks] = ahN[ks]; alC[ks] = alN[ks]; }
#pragma unroll
            for (int r = 0; r < 4; ++r) cC[r] = cN[r];
        }
    }

#pragma unroll
    for (int kt = 0; kt < 8; ++kt)
#pragma unroll
        for (int r = 0; r < 4; ++r) {
            const int q = q0 + w * 16 + quad * 4 + r;
            avg[((long long)(b * SEQ + q)) * SEQ + k0 + kt * 16 + lid] = acc[kt][r];
        }
}

// ---------------------------------------------------------------------------
extern "C" void kernel_launch(void* const* d_in, const int* in_sizes, int n_in,
                              void* d_out, int out_size, void* d_ws, size_t ws_size,
                              hipStream_t stream)
{
    const float* query = (const float*)d_in[0];
    const float* key   = (const float*)d_in[1];
    const float* value = (const float*)d_in[2];
    const float* Wq    = (const float*)d_in[3];
    const float* bq    = (const float*)d_in[4];
    const float* Wk    = (const float*)d_in[5];
    const float* bk    = (const float*)d_in[6];
    const float* Wv    = (const float*)d_in[7];
    const float* bv    = (const float*)d_in[8];
    const float* Wo    = (const float*)d_in[9];
    const float* bo    = (const float*)d_in[10];

    float* out = (float*)d_out;                         // [B,S,DMODEL]
    float* avg = out + (long long)BATCH * SEQ * DMODEL; // [B,S,S]

    const long long QKN = (long long)MROWS * DMODEL;    // 4.2M elems
    unsigned short* QfH = (unsigned short*)d_ws;        // frag-major, 8 MB each
    unsigned short* QfL = QfH + QKN;
    unsigned short* Khi = QfL + QKN;                    // row-major
    unsigned short* Klo = Khi + QKN;
    unsigned short* AspH = Klo + QKN;                   // split input scratch (reused)
    unsigned short* AspL = AspH + QKN;
    unsigned short* WTh  = AspL + QKN;                  // W^T split, 2 MB each
    unsigned short* WTl  = WTh + (long long)DMODEL * DMODEL;
    float* Vb   = (float*)(WTl + (long long)DMODEL * DMODEL); // 4096x64 fp32
    float* lBuf = Vb + (long long)MROWS * DK;                 // B*H*S
    float* ao   = lBuf + (long long)BATCH * NHEAD * SEQ;      // 4096x64

    // Dead-region reuse for split-K partials (in-stream ordering guarantees):
    //  - V proj partials (16 x 1 MB) live in AspH..AspL (dead after proj_mfma(K)).
    //  - avg@V partials (32 x 1 MB) live in QfH..Klo (dead after attn_avg).
    float* Pv  = (float*)AspH;
    float* Pav = (float*)QfH;

    dim3 blk(256);
    hipMemsetAsync(lBuf, 0, (size_t)BATCH * NHEAD * SEQ * sizeof(float), stream);

    const int convGrid = (int)(QKN / (256 * 4));        // 4096
    dim3 tGrid(DMODEL / 64, DMODEL / 64);               // 16x16
    dim3 pGrid(DMODEL / 64, MROWS / 128);               // 16x32 = 512 blocks

    // Q projection (MFMA split-bf16), emits fragment-major Q hi/lo,
    // pre-scaled by 1/8 (folds softmax scale; bit-exact).
    conv_split_kernel<<<convGrid, blk, 0, stream>>>(query, AspH, AspL);
    conv_splitT_kernel<<<tGrid, blk, 0, stream>>>(Wq, WTh, WTl);
    proj_mfma_kernel<<<pGrid, blk, 0, stream>>>(AspH, AspL, WTh, WTl, bq, QfH, QfL, 1, 0.125f);

    // K projection (MFMA split-bf16), emits row-major K hi/lo.  Scratch reused.
    conv_split_kernel<<<convGrid, blk, 0, stream>>>(key, AspH, AspL);
    conv_splitT_kernel<<<tGrid, blk, 0, stream>>>(Wk, WTh, WTl);
    proj_mfma_kernel<<<pGrid, blk, 0, stream>>>(AspH, AspL, WTh, WTl, bk, Khi, Klo, 0, 1.0f);

    // V projection: split-K fp32 (16 splits -> 1024 blocks), then reduce+bias.
    gemm_splitk_kernel<<<dim3(DK / 64, MROWS / 64, 16), blk, 0, stream>>>(
        value, 0, Wv, 0, Pv, MROWS, DK, DMODEL, 16);
    reduce_bias_kernel<<<dim3((int)((long long)MROWS * DK / 1024)), blk, 0, stream>>>(
        Pv, bv, Vb, (long long)MROWS * DK, 16, DK);

    // Softmax denominators (k-split partial sums), then reciprocal (once).
    attn_stats_kernel<<<dim3(SEQ / 256, NHEAD, BATCH * KSPLIT), dim3(512), 0, stream>>>(
        QfH, QfL, Khi, Klo, lBuf);
    recip_kernel<<<dim3(BATCH * NHEAD * SEQ / 256), blk, 0, stream>>>(lBuf);

    // Head-averaged attention matrix.
    attn_avg_kernel<<<dim3(SEQ / 128, SEQ / 128, BATCH), dim3(512), 0, stream>>>(
        QfH, QfL, Khi, Klo, lBuf, avg);

    // attn_output = avg_attn @ V: split-K fp32 (32 splits x 2 batches -> 2048
    // blocks) into dead Qf/K region, then reduce (no bias).
    gemm_splitk_kernel<<<dim3(DK / 64, SEQ / 64, BATCH * 32), blk, 0, stream>>>(
        avg, (long long)SEQ * SEQ, Vb, (long long)SEQ * DK, Pav, SEQ, DK, SEQ, 32);
    reduce_bias_kernel<<<dim3((int)((long long)MROWS * DK / 1024)), blk, 0, stream>>>(
        Pav, nullptr, ao, (long long)MROWS * DK, 32, DK);

    // output = attn_output @ Wo + bo
    gemm_bias_kernel<<<dim3(DMODEL / 64, MROWS / 64, 1), blk, 0, stream>>>(
        ao, 0, Wo, 0, bo, out, 0, MROWS, DMODEL, DK);
}